// Round 9
// baseline (209.629 us; speedup 1.0000x reference)
//
#include <hip/hip_runtime.h>
#include <math.h>

// Problem constants (match reference)
#define BATCH 4
#define NK    100000
#define IH    640
#define IW    472
#define GH    1280          // oversampled grid rows = 2*IH   (1280 = 20*8*8)
#define GW    944           // oversampled grid cols = 2*IW   (944  = 59*16)
#define GWP   952           // padded row stride: 8 echo cols for wrap-free float4 windows
#define JW    6             // KB kernel width

// twiddle table layout in ws (units: float2): W_N^t = exp(-2*pi*i*t/N)
#define TW1280_OFF 0
#define TW944_OFF  1280
#define TW_RESERVE_BYTES 32768

#define NC      4            // columns per fft_col block
#define CSTRIDE 4            // LDS slot stride (float2): 40 KB buf -> 4 blocks/CU

static __device__ __forceinline__ float beta_f() {
    return (float)(M_PI * 4.410215414239989);   // pi*sqrt(19.45)
}

// Abramowitz & Stegun I0 approximation (rel err < 2e-7), x >= 0
static __device__ __forceinline__ float i0f_dev(float x) {
    if (x < 3.75f) {
        float t = x * (1.0f / 3.75f);
        t *= t;
        return 1.0f + t*(3.5156229f + t*(3.0899424f + t*(1.2067492f +
               t*(0.2659732f + t*(0.0360768f + t*0.0045813f)))));
    } else {
        float t = 3.75f / x;
        float p = 0.39894228f + t*(0.01328592f + t*(0.00225319f + t*(-0.00157565f +
                  t*(0.00916281f + t*(-0.02057706f + t*(0.02635537f +
                  t*(-0.01647633f + t*0.00392377f)))))));
        return p * expf(x) / sqrtf(x);
    }
}

static __device__ __forceinline__ float2 cmul(float2 a, float2 b) {
    return make_float2(a.x * b.x - a.y * b.y, a.x * b.y + a.y * b.x);
}

// ---------------------------------------------------------------------------
// Kernel 0: twiddle tables (5 blocks)
// ---------------------------------------------------------------------------
__global__ __launch_bounds__(256) void twiddle_init_kernel(float2* __restrict__ tw)
{
    int idx = blockIdx.x * 256 + threadIdx.x;
    const double TWO_PI = 6.283185307179586476925286766559;
    if (idx < 1280) {
        double a = -TWO_PI * ((double)idx / 1280.0);
        tw[TW1280_OFF + idx] = make_float2((float)cos(a), (float)sin(a));
    }
    if (idx < 944) {
        double a = -TWO_PI * ((double)idx / 944.0);
        tw[TW944_OFF + idx] = make_float2((float)cos(a), (float)sin(a));
    }
}

// ---------------------------------------------------------------------------
// Kernel 1: FUSED apodize+pad+ifftshift+scale + length-944 row FFT (16*59 DIT)
// ---------------------------------------------------------------------------
__global__ __launch_bounds__(256) void fft_row_kernel(
        const float* __restrict__ ir, const float* __restrict__ ii,
        float2* __restrict__ grid, const float2* __restrict__ twg,
        int b0, int nb)
{
    __shared__ float2 buf[GW];            // 7552 B

    int blk = blockIdx.x;                 // nb*IH blocks
    int lb = blk / IH;
    int ri = blk % IH;
    int b  = b0 + lb;
    int u  = (ri < 320) ? ri : ri + 640;
    int i  = (ri < 320) ? ri + 320 : ri - 320;
    float2* row = grid + ((size_t)(lb * GH + u)) * GWP;
    int tid = threadIdx.x;
    const float2* tw = twg + TW944_OFF;

    // row-constant apodization factor ax(i)
    const float B2 = (float)(M_PI * M_PI * 19.45);   // BETA^2
    float xi = (float)(i - IH / 2) * (1.0f / (float)GH);
    float px = (float)(M_PI * (double)JW) * xi;
    float sxr = sqrtf(B2 - px * px);
    float ax = (float)JW * sinhf(sxr) / sxr;
    const float SCALE = (float)(1.0 / 1099.236098591787);  // 1/sqrt(1280*944)
    float rowscale = SCALE / ax;
    const float* irow  = ir + (size_t)(b * IH + i) * IW;
    const float* iirow = ii + (size_t)(b * IH + i) * IW;

    for (int t = tid; t < GW; t += 256) {
        float2 val = make_float2(0.f, 0.f);
        int j = -1;
        if (t < (GW - IW) / 2) j = t + IW / 2;               // 236..471
        else if (t >= (GW + IW) / 2) j = t - (GW + IW) / 2;  // 0..235
        if (j >= 0) {
            float yj = (float)(j - IW / 2) * (1.0f / (float)GW);
            float py = (float)(M_PI * (double)JW) * yj;
            float syr = sqrtf(B2 - py * py);
            float ay = (float)JW * sinhf(syr) / syr;
            float invA = rowscale / ay;
            val.x = irow[j] * invA;
            val.y = iirow[j] * invA;
        }
        buf[t] = val;
    }
    __syncthreads();

    // stage 1 -> registers (zero cols skipped: n1 in {0..14, 44..58})
    float2 z[4];
    #pragma unroll
    for (int it = 0; it < 4; ++it) {
        int o = it * 256 + tid;
        if (o < GW) {
            int k1 = o % 59;
            int n2 = o / 59;
            float2 r = tw[16 * k1];                       // W59^{k1}
            float2 w = make_float2(1.f, 0.f);
            float re = 0.f, im = 0.f;
            for (int n1 = 0; n1 < 15; ++n1) {
                float2 x = buf[(n1 << 4) + n2];
                re += x.x * w.x - x.y * w.y;
                im += x.x * w.y + x.y * w.x;
                w = cmul(w, r);
            }
            w = tw[16 * ((44 * k1) % 59)];                // W59^{44 k1}
            for (int n1 = 44; n1 < 59; ++n1) {
                float2 x = buf[(n1 << 4) + n2];
                re += x.x * w.x - x.y * w.y;
                im += x.x * w.y + x.y * w.x;
                w = cmul(w, r);
            }
            float2 tp = tw[n2 * k1];
            z[it] = make_float2(re * tp.x - im * tp.y, re * tp.y + im * tp.x);
        }
    }
    __syncthreads();
    #pragma unroll
    for (int it = 0; it < 4; ++it) {
        int o = it * 256 + tid;
        if (o < GW) buf[o] = z[it];
    }
    __syncthreads();

    // stage 2 -> global
    #pragma unroll
    for (int it = 0; it < 4; ++it) {
        int o = it * 256 + tid;
        if (o < GW) {
            int k1 = o % 59;
            int k2 = o / 59;
            float2 r = tw[59 * k2];                       // W16^{k2}
            float2 w = make_float2(1.f, 0.f);
            float re = 0.f, im = 0.f;
            for (int n2 = 0; n2 < 16; ++n2) {
                float2 x = buf[n2 * 59 + k1];
                re += x.x * w.x - x.y * w.y;
                im += x.x * w.y + x.y * w.x;
                w = cmul(w, r);
            }
            row[o] = make_float2(re, im);
        }
    }
}

// ---------------------------------------------------------------------------
// Kernel 2: length-1280 column FFT, 3-stage DIT 1280 = 20*8*8, 4 cols/block.
// Zero rows [320,960) skipped in stage A and never fetched. Blocks vb<2 also
// write the echo columns [944,952) (wrap band) in stage C.
// ---------------------------------------------------------------------------
__global__ __launch_bounds__(256) void fft_col_kernel(
        float2* __restrict__ grid, const float2* __restrict__ twg)
{
    __shared__ float2 buf[GH * CSTRIDE];   // 40960 B -> 4 blocks/CU

    int blk = blockIdx.x;                  // nb * 236
    int lb = blk / (GW / NC);
    int vb = blk % (GW / NC);
    float2* base = grid + (size_t)lb * GH * GWP + vb * NC;
    int tid = threadIdx.x;
    const float2* tw = twg + TW1280_OFF;

    // load (nonzero rows only; zero-fill the pad band)
    #pragma unroll
    for (int it = 0; it < 20; ++it) {
        int item = it * 256 + tid;
        int c = item & (NC - 1);
        int u = item >> 2;
        float2 v = make_float2(0.f, 0.f);
        if (u < 320 || u >= 960) v = base[(size_t)u * GWP + c];
        buf[u * CSTRIDE + c] = v;
    }
    __syncthreads();

    float2 z[20];

    // ---- stage A: radix-20 with zero-skip; slot o = m*20 + k1
    #pragma unroll
    for (int it = 0; it < 20; ++it) {
        int item = it * 256 + tid;
        int c = item & 3;
        int o = item >> 2;
        int k1 = o % 20;
        int m  = o / 20;
        float2 r = tw[64 * k1];                           // W20^{k1}
        float2 w = make_float2(1.f, 0.f);
        float re = 0.f, im = 0.f;
        for (int n1 = 0; n1 < 5; ++n1) {
            float2 x = buf[((n1 << 6) + m) * CSTRIDE + c];
            re += x.x * w.x - x.y * w.y;
            im += x.x * w.y + x.y * w.x;
            w = cmul(w, r);
        }
        w = tw[64 * ((15 * k1) % 20)];                    // W20^{15 k1}
        for (int n1 = 15; n1 < 20; ++n1) {
            float2 x = buf[((n1 << 6) + m) * CSTRIDE + c];
            re += x.x * w.x - x.y * w.y;
            im += x.x * w.y + x.y * w.x;
            w = cmul(w, r);
        }
        float2 tp = tw[m * k1];
        z[it] = make_float2(re * tp.x - im * tp.y, re * tp.y + im * tp.x);
    }
    __syncthreads();
    #pragma unroll
    for (int it = 0; it < 20; ++it) {
        int item = it * 256 + tid;
        buf[(item >> 2) * CSTRIDE + (item & 3)] = z[it];
    }
    __syncthreads();

    // ---- stage B: radix-8 over m1
    #pragma unroll
    for (int it = 0; it < 20; ++it) {
        int item = it * 256 + tid;
        int c   = item & 3;
        int o2  = item >> 2;
        int k21 = o2 & 7;
        int t2  = o2 >> 3;           // = m2*20 + k1
        int k1  = t2 % 20;
        int m2  = t2 / 20;
        float2 r = tw[160 * k21];                         // W8^{k21}
        float2 w = make_float2(1.f, 0.f);
        float re = 0.f, im = 0.f;
        for (int m1 = 0; m1 < 8; ++m1) {
            float2 x = buf[(((m1 << 3) + m2) * 20 + k1) * CSTRIDE + c];
            re += x.x * w.x - x.y * w.y;
            im += x.x * w.y + x.y * w.x;
            w = cmul(w, r);
        }
        float2 tp = tw[20 * m2 * k21];                    // W64^{m2 k21}
        z[it] = make_float2(re * tp.x - im * tp.y, re * tp.y + im * tp.x);
    }
    __syncthreads();
    #pragma unroll
    for (int it = 0; it < 20; ++it) {
        int item = it * 256 + tid;
        buf[(item >> 2) * CSTRIDE + (item & 3)] = z[it];
    }
    __syncthreads();

    // ---- stage C: radix-8 over m2 -> global (+ echo cols for vb<2)
    #pragma unroll
    for (int it = 0; it < 20; ++it) {
        int item = it * 256 + tid;
        int c   = item & 3;
        int o3  = item >> 2;
        int k22 = o3 & 7;
        int t3  = o3 >> 3;           // = k1*8 + k21
        int k21 = t3 & 7;
        int k1  = t3 >> 3;
        float2 r = tw[160 * k22];                         // W8^{k22}
        float2 w = make_float2(1.f, 0.f);
        float re = 0.f, im = 0.f;
        for (int m2 = 0; m2 < 8; ++m2) {
            float2 x = buf[((m2 * 20 + k1) * 8 + k21) * CSTRIDE + c];
            re += x.x * w.x - x.y * w.y;
            im += x.x * w.y + x.y * w.x;
            w = cmul(w, r);
        }
        int rrow = k1 + 20 * k21 + 160 * k22;
        float2 res = make_float2(re, im);
        base[(size_t)rrow * GWP + c] = res;
        if (vb < 2) base[(size_t)rrow * GWP + GW + c] = res;   // echo cols 0..7
    }
}

// ---------------------------------------------------------------------------
// Kernel 3: KB interpolation, 2 lanes per point. Lane parity h handles x-taps
// {3h,3h+1,3h+2}; each lane issues 12 independent float4 loads; partial sums
// combined via shfl_xor(1); even lane writes.
// ---------------------------------------------------------------------------
__global__ __launch_bounds__(256) void interp_kernel(
        const float* __restrict__ ktraj, const float2* __restrict__ grid,
        float* __restrict__ out, int b0, int nb, int write_complex)
{
    int idx = blockIdx.x * 256 + threadIdx.x;
    if (idx >= nb * NK * 2) return;
    int h   = idx & 1;                 // half: 0 -> x-taps 0..2, 1 -> 3..5
    int pnt = idx >> 1;
    int lb = pnt / NK;
    int k  = pnt % NK;
    int b  = b0 + lb;

    const float BETA = beta_f();
    float t0 = ktraj[(size_t)(b * 2 + 0) * NK + k] * (float)((double)GH / (2.0 * M_PI));
    float t1 = ktraj[(size_t)(b * 2 + 1) * NK + k] * (float)((double)GW / (2.0 * M_PI));
    int base0 = (int)floorf(t0);
    int base1 = (int)floorf(t1);

    // x: this lane's 3 wrapped rows + weights
    float wx[3];
    int   ix[3];
    #pragma unroll
    for (int j = 0; j < 3; ++j) {
        int jj = h * 3 + j;
        int kx = base0 + jj - (JW / 2 - 1);
        float u = t0 - (float)kx;
        float q = u * (1.0f / 3.0f);
        float zz = 1.0f - q * q;
        wx[j] = (zz > 0.f) ? i0f_dev(BETA * sqrtf(zz)) : 0.f;
        int m = kx % GH; if (m < 0) m += GH;
        ix[j] = m;
    }

    // y: even-aligned 8-tap window; taps outside |u|<3 get w=0
    int j0u = base1 - 2;
    int a0u = j0u - (j0u & 1);
    int aw  = a0u; if (aw < 0) aw += GW;   // [0,942] even -> 16B-aligned
    float wy8[8];
    #pragma unroll
    for (int t = 0; t < 8; ++t) {
        float u = t1 - (float)(a0u + t);
        float q = u * (1.0f / 3.0f);
        float zz = 1.0f - q * q;
        wy8[t] = (zz > 0.f) ? i0f_dev(BETA * sqrtf(zz)) : 0.f;
    }

    // 12 independent float4 loads (3 rows x 4)
    float4 v[3][4];
    #pragma unroll
    for (int a = 0; a < 3; ++a) {
        const float4* p4 = (const float4*)(grid + ((size_t)(lb * GH + ix[a])) * GWP + aw);
        v[a][0] = p4[0]; v[a][1] = p4[1]; v[a][2] = p4[2]; v[a][3] = p4[3];
    }

    float accre = 0.f, accim = 0.f;
    #pragma unroll
    for (int a = 0; a < 3; ++a) {
        float rre = wy8[0]*v[a][0].x + wy8[1]*v[a][0].z + wy8[2]*v[a][1].x + wy8[3]*v[a][1].z
                  + wy8[4]*v[a][2].x + wy8[5]*v[a][2].z + wy8[6]*v[a][3].x + wy8[7]*v[a][3].z;
        float rim = wy8[0]*v[a][0].y + wy8[1]*v[a][0].w + wy8[2]*v[a][1].y + wy8[3]*v[a][1].w
                  + wy8[4]*v[a][2].y + wy8[5]*v[a][2].w + wy8[6]*v[a][3].y + wy8[7]*v[a][3].w;
        accre += wx[a] * rre;
        accim += wx[a] * rim;
    }

    // combine the two halves
    accre += __shfl_xor(accre, 1);
    accim += __shfl_xor(accim, 1);

    if (h == 0) {
        size_t p = (size_t)b * NK + k;
        if (write_complex) {
            ((float2*)out)[p] = make_float2(accre, accim);
        } else {
            out[p] = accre;
        }
    }
}

// ---------------------------------------------------------------------------
extern "C" void kernel_launch(void* const* d_in, const int* in_sizes, int n_in,
                              void* d_out, int out_size, void* d_ws, size_t ws_size,
                              hipStream_t stream)
{
    const float* ir = (const float*)d_in[0];   // [B,640,472,1] float32
    const float* ii = (const float*)d_in[1];   // [B,640,472,1] float32
    const float* kt = (const float*)d_in[2];   // [B,2,K] float32
    float2* tw   = (float2*)d_ws;
    float2* grid = (float2*)((char*)d_ws + TW_RESERVE_BYTES);
    float*  out  = (float*)d_out;

    int write_complex = (out_size >= 2 * BATCH * NK) ? 1 : 0;

    const size_t per_batch = (size_t)GH * GWP * sizeof(float2);  // 9.75 MB
    size_t avail = (ws_size > TW_RESERVE_BYTES) ? ws_size - TW_RESERVE_BYTES : 0;
    int nb = 1;
    if (avail >= 4 * per_batch)      nb = 4;
    else if (avail >= 2 * per_batch) nb = 2;

    twiddle_init_kernel<<<5, 256, 0, stream>>>(tw);

    for (int b0 = 0; b0 < BATCH; b0 += nb) {
        fft_row_kernel<<<nb * IH, 256, 0, stream>>>(ir, ii, grid, tw, b0, nb);
        fft_col_kernel<<<nb * (GW / NC), 256, 0, stream>>>(grid, tw);
        interp_kernel<<<(nb * NK * 2 + 255) / 256, 256, 0, stream>>>(kt, grid, out, b0, nb, write_complex);
    }
}

// Round 10
// 181.753 us; speedup vs baseline: 1.1534x; 1.1534x over previous
//
#include <hip/hip_runtime.h>
#include <math.h>

// Problem constants (match reference)
#define BATCH 4
#define NK    100000
#define IH    640
#define IW    472
#define GH    1280          // oversampled grid rows = 2*IH   (1280 = 20*8*8)
#define GW    944           // oversampled grid cols = 2*IW   (944  = 59*16)
#define GWP   952           // padded row stride: 8 echo cols (window reach <= 951)
#define JW    6             // KB kernel width

// twiddle table layout in ws (units: float2): W_N^t = exp(-2*pi*i*t/N)
#define TW1280_OFF 0
#define TW944_OFF  1280
#define TW_RESERVE_BYTES 32768

#define NC      4            // columns per fft_col block
#define CSTRIDE 4            // LDS slot stride (float2): 40 KB buf -> 4 blocks/CU

static __device__ __forceinline__ float beta_f() {
    return (float)(M_PI * 4.410215414239989);   // pi*sqrt(19.45)
}

// Abramowitz & Stegun I0 approximation (rel err < 2e-7), x >= 0
static __device__ __forceinline__ float i0f_dev(float x) {
    if (x < 3.75f) {
        float t = x * (1.0f / 3.75f);
        t *= t;
        return 1.0f + t*(3.5156229f + t*(3.0899424f + t*(1.2067492f +
               t*(0.2659732f + t*(0.0360768f + t*0.0045813f)))));
    } else {
        float t = 3.75f / x;
        float p = 0.39894228f + t*(0.01328592f + t*(0.00225319f + t*(-0.00157565f +
                  t*(0.00916281f + t*(-0.02057706f + t*(0.02635537f +
                  t*(-0.01647633f + t*0.00392377f)))))));
        return p * expf(x) / sqrtf(x);
    }
}

static __device__ __forceinline__ float2 cmul(float2 a, float2 b) {
    return make_float2(a.x * b.x - a.y * b.y, a.x * b.y + a.y * b.x);
}

// float -> bf16 bits (round-nearest-even)
static __device__ __forceinline__ unsigned int f2bf(float f) {
    unsigned int u = __float_as_uint(f);
    return (u + 0x7FFFu + ((u >> 16) & 1u)) >> 16;
}

// ---------------------------------------------------------------------------
// Kernel 0: twiddle tables (5 blocks)
// ---------------------------------------------------------------------------
__global__ __launch_bounds__(256) void twiddle_init_kernel(float2* __restrict__ tw)
{
    int idx = blockIdx.x * 256 + threadIdx.x;
    const double TWO_PI = 6.283185307179586476925286766559;
    if (idx < 1280) {
        double a = -TWO_PI * ((double)idx / 1280.0);
        tw[TW1280_OFF + idx] = make_float2((float)cos(a), (float)sin(a));
    }
    if (idx < 944) {
        double a = -TWO_PI * ((double)idx / 944.0);
        tw[TW944_OFF + idx] = make_float2((float)cos(a), (float)sin(a));
    }
}

// ---------------------------------------------------------------------------
// Kernel 1: FUSED apodize+pad+ifftshift+scale + length-944 row FFT (16*59 DIT)
// ---------------------------------------------------------------------------
__global__ __launch_bounds__(256) void fft_row_kernel(
        const float* __restrict__ ir, const float* __restrict__ ii,
        float2* __restrict__ grid, const float2* __restrict__ twg,
        int b0, int nb)
{
    __shared__ float2 buf[GW];            // 7552 B

    int blk = blockIdx.x;                 // nb*IH blocks
    int lb = blk / IH;
    int ri = blk % IH;
    int b  = b0 + lb;
    int u  = (ri < 320) ? ri : ri + 640;
    int i  = (ri < 320) ? ri + 320 : ri - 320;
    float2* row = grid + ((size_t)(lb * GH + u)) * GWP;
    int tid = threadIdx.x;
    const float2* tw = twg + TW944_OFF;

    // row-constant apodization factor ax(i)
    const float B2 = (float)(M_PI * M_PI * 19.45);   // BETA^2
    float xi = (float)(i - IH / 2) * (1.0f / (float)GH);
    float px = (float)(M_PI * (double)JW) * xi;
    float sxr = sqrtf(B2 - px * px);
    float ax = (float)JW * sinhf(sxr) / sxr;
    const float SCALE = (float)(1.0 / 1099.236098591787);  // 1/sqrt(1280*944)
    float rowscale = SCALE / ax;
    const float* irow  = ir + (size_t)(b * IH + i) * IW;
    const float* iirow = ii + (size_t)(b * IH + i) * IW;

    for (int t = tid; t < GW; t += 256) {
        float2 val = make_float2(0.f, 0.f);
        int j = -1;
        if (t < (GW - IW) / 2) j = t + IW / 2;               // 236..471
        else if (t >= (GW + IW) / 2) j = t - (GW + IW) / 2;  // 0..235
        if (j >= 0) {
            float yj = (float)(j - IW / 2) * (1.0f / (float)GW);
            float py = (float)(M_PI * (double)JW) * yj;
            float syr = sqrtf(B2 - py * py);
            float ay = (float)JW * sinhf(syr) / syr;
            float invA = rowscale / ay;
            val.x = irow[j] * invA;
            val.y = iirow[j] * invA;
        }
        buf[t] = val;
    }
    __syncthreads();

    // stage 1 -> registers (zero cols skipped: n1 in {0..14, 44..58})
    float2 z[4];
    #pragma unroll
    for (int it = 0; it < 4; ++it) {
        int o = it * 256 + tid;
        if (o < GW) {
            int k1 = o % 59;
            int n2 = o / 59;
            float2 r = tw[16 * k1];                       // W59^{k1}
            float2 w = make_float2(1.f, 0.f);
            float re = 0.f, im = 0.f;
            for (int n1 = 0; n1 < 15; ++n1) {
                float2 x = buf[(n1 << 4) + n2];
                re += x.x * w.x - x.y * w.y;
                im += x.x * w.y + x.y * w.x;
                w = cmul(w, r);
            }
            w = tw[16 * ((44 * k1) % 59)];                // W59^{44 k1}
            for (int n1 = 44; n1 < 59; ++n1) {
                float2 x = buf[(n1 << 4) + n2];
                re += x.x * w.x - x.y * w.y;
                im += x.x * w.y + x.y * w.x;
                w = cmul(w, r);
            }
            float2 tp = tw[n2 * k1];
            z[it] = make_float2(re * tp.x - im * tp.y, re * tp.y + im * tp.x);
        }
    }
    __syncthreads();
    #pragma unroll
    for (int it = 0; it < 4; ++it) {
        int o = it * 256 + tid;
        if (o < GW) buf[o] = z[it];
    }
    __syncthreads();

    // stage 2 -> global
    #pragma unroll
    for (int it = 0; it < 4; ++it) {
        int o = it * 256 + tid;
        if (o < GW) {
            int k1 = o % 59;
            int k2 = o / 59;
            float2 r = tw[59 * k2];                       // W16^{k2}
            float2 w = make_float2(1.f, 0.f);
            float re = 0.f, im = 0.f;
            for (int n2 = 0; n2 < 16; ++n2) {
                float2 x = buf[n2 * 59 + k1];
                re += x.x * w.x - x.y * w.y;
                im += x.x * w.y + x.y * w.x;
                w = cmul(w, r);
            }
            row[o] = make_float2(re, im);
        }
    }
}

// ---------------------------------------------------------------------------
// Kernel 2: length-1280 column FFT, 3-stage DIT 1280 = 20*8*8, 4 cols/block.
// Reads fp32 grid (fft_row output); WRITES packed-bf16 grid for interp
// (uint = re_bf16 | im_bf16<<16). Blocks vb<2 also write echo cols [944,952).
// ---------------------------------------------------------------------------
__global__ __launch_bounds__(256) void fft_col_kernel(
        const float2* __restrict__ grid, unsigned int* __restrict__ gridh,
        const float2* __restrict__ twg)
{
    __shared__ float2 buf[GH * CSTRIDE];   // 40960 B -> 4 blocks/CU

    int blk = blockIdx.x;                  // nb * 236
    int lb = blk / (GW / NC);
    int vb = blk % (GW / NC);
    const float2* base = grid + (size_t)lb * GH * GWP + vb * NC;
    unsigned int* baseh = gridh + (size_t)lb * GH * GWP + vb * NC;
    int tid = threadIdx.x;
    const float2* tw = twg + TW1280_OFF;

    // load (nonzero rows only; zero-fill the pad band)
    #pragma unroll
    for (int it = 0; it < 20; ++it) {
        int item = it * 256 + tid;
        int c = item & (NC - 1);
        int u = item >> 2;
        float2 v = make_float2(0.f, 0.f);
        if (u < 320 || u >= 960) v = base[(size_t)u * GWP + c];
        buf[u * CSTRIDE + c] = v;
    }
    __syncthreads();

    float2 z[20];

    // ---- stage A: radix-20 with zero-skip; slot o = m*20 + k1
    #pragma unroll
    for (int it = 0; it < 20; ++it) {
        int item = it * 256 + tid;
        int c = item & 3;
        int o = item >> 2;
        int k1 = o % 20;
        int m  = o / 20;
        float2 r = tw[64 * k1];                           // W20^{k1}
        float2 w = make_float2(1.f, 0.f);
        float re = 0.f, im = 0.f;
        for (int n1 = 0; n1 < 5; ++n1) {
            float2 x = buf[((n1 << 6) + m) * CSTRIDE + c];
            re += x.x * w.x - x.y * w.y;
            im += x.x * w.y + x.y * w.x;
            w = cmul(w, r);
        }
        w = tw[64 * ((15 * k1) % 20)];                    // W20^{15 k1}
        for (int n1 = 15; n1 < 20; ++n1) {
            float2 x = buf[((n1 << 6) + m) * CSTRIDE + c];
            re += x.x * w.x - x.y * w.y;
            im += x.x * w.y + x.y * w.x;
            w = cmul(w, r);
        }
        float2 tp = tw[m * k1];
        z[it] = make_float2(re * tp.x - im * tp.y, re * tp.y + im * tp.x);
    }
    __syncthreads();
    #pragma unroll
    for (int it = 0; it < 20; ++it) {
        int item = it * 256 + tid;
        buf[(item >> 2) * CSTRIDE + (item & 3)] = z[it];
    }
    __syncthreads();

    // ---- stage B: radix-8 over m1
    #pragma unroll
    for (int it = 0; it < 20; ++it) {
        int item = it * 256 + tid;
        int c   = item & 3;
        int o2  = item >> 2;
        int k21 = o2 & 7;
        int t2  = o2 >> 3;           // = m2*20 + k1
        int k1  = t2 % 20;
        int m2  = t2 / 20;
        float2 r = tw[160 * k21];                         // W8^{k21}
        float2 w = make_float2(1.f, 0.f);
        float re = 0.f, im = 0.f;
        for (int m1 = 0; m1 < 8; ++m1) {
            float2 x = buf[(((m1 << 3) + m2) * 20 + k1) * CSTRIDE + c];
            re += x.x * w.x - x.y * w.y;
            im += x.x * w.y + x.y * w.x;
            w = cmul(w, r);
        }
        float2 tp = tw[20 * m2 * k21];                    // W64^{m2 k21}
        z[it] = make_float2(re * tp.x - im * tp.y, re * tp.y + im * tp.x);
    }
    __syncthreads();
    #pragma unroll
    for (int it = 0; it < 20; ++it) {
        int item = it * 256 + tid;
        buf[(item >> 2) * CSTRIDE + (item & 3)] = z[it];
    }
    __syncthreads();

    // ---- stage C: radix-8 over m2 -> packed bf16 global (+ echo for vb<2)
    #pragma unroll
    for (int it = 0; it < 20; ++it) {
        int item = it * 256 + tid;
        int c   = item & 3;
        int o3  = item >> 2;
        int k22 = o3 & 7;
        int t3  = o3 >> 3;           // = k1*8 + k21
        int k21 = t3 & 7;
        int k1  = t3 >> 3;
        float2 r = tw[160 * k22];                         // W8^{k22}
        float2 w = make_float2(1.f, 0.f);
        float re = 0.f, im = 0.f;
        for (int m2 = 0; m2 < 8; ++m2) {
            float2 x = buf[((m2 * 20 + k1) * 8 + k21) * CSTRIDE + c];
            re += x.x * w.x - x.y * w.y;
            im += x.x * w.y + x.y * w.x;
            w = cmul(w, r);
        }
        int rrow = k1 + 20 * k21 + 160 * k22;
        unsigned int pk = f2bf(re) | (f2bf(im) << 16);
        baseh[(size_t)rrow * GWP + c] = pk;
        if (vb < 2) baseh[(size_t)rrow * GWP + GW + c] = pk;   // echo cols 0..7
    }
}

// ---------------------------------------------------------------------------
// Kernel 3: KB interpolation from packed-bf16 grid. One thread per point.
// Y: 12-tap window aligned to 4 taps -> 3 x uint4 (16 B) loads per row;
// taps outside |u|<3 get zero weight. X: 6 wrapped rows.
// ---------------------------------------------------------------------------
__global__ __launch_bounds__(256) void interp_kernel(
        const float* __restrict__ ktraj, const unsigned int* __restrict__ gridh,
        float* __restrict__ out, int b0, int nb, int write_complex)
{
    int idx = blockIdx.x * 256 + threadIdx.x;
    if (idx >= nb * NK) return;
    int lb = idx / NK;
    int k  = idx % NK;
    int b  = b0 + lb;

    const float BETA = beta_f();
    float t0 = ktraj[(size_t)(b * 2 + 0) * NK + k] * (float)((double)GH / (2.0 * M_PI));
    float t1 = ktraj[(size_t)(b * 2 + 1) * NK + k] * (float)((double)GW / (2.0 * M_PI));
    int base0 = (int)floorf(t0);
    int base1 = (int)floorf(t1);

    // x: 6 wrapped rows + weights
    float wx[JW];
    int   ix[JW];
    #pragma unroll
    for (int j = 0; j < JW; ++j) {
        int kx = base0 + j - (JW / 2 - 1);
        float u = t0 - (float)kx;
        float q = u * (1.0f / 3.0f);
        float zz = 1.0f - q * q;
        wx[j] = (zz > 0.f) ? i0f_dev(BETA * sqrtf(zz)) : 0.f;
        int m = kx % GH; if (m < 0) m += GH;
        ix[j] = m;
    }

    // y: 12-tap window aligned to 4 taps (16-B aligned in packed-bf16 grid)
    int j0u = base1 - 2;
    int a0u = j0u & ~3;                    // rounds toward -inf, mult of 4
    int aw  = a0u; if (aw < 0) aw += GW;   // [0,940], mult of 4
    float wy12[12];
    #pragma unroll
    for (int t = 0; t < 12; ++t) {
        float u = t1 - (float)(a0u + t);
        float q = u * (1.0f / 3.0f);
        float zz = 1.0f - q * q;
        wy12[t] = (zz > 0.f) ? i0f_dev(BETA * sqrtf(zz)) : 0.f;
    }

    float accre = 0.f, accim = 0.f;
    #pragma unroll
    for (int a = 0; a < JW; ++a) {
        const uint4* p4 = (const uint4*)(gridh + ((size_t)(lb * GH + ix[a])) * GWP + aw);
        uint4 q0 = p4[0];
        uint4 q1 = p4[1];
        uint4 q2 = p4[2];
        float rre = 0.f, rim = 0.f;
        unsigned int qs[12] = {q0.x, q0.y, q0.z, q0.w, q1.x, q1.y, q1.z, q1.w,
                               q2.x, q2.y, q2.z, q2.w};
        #pragma unroll
        for (int t = 0; t < 12; ++t) {
            float gre = __uint_as_float(qs[t] << 16);
            float gim = __uint_as_float(qs[t] & 0xFFFF0000u);
            rre += wy12[t] * gre;
            rim += wy12[t] * gim;
        }
        accre += wx[a] * rre;
        accim += wx[a] * rim;
    }
    size_t p = (size_t)b * NK + k;
    if (write_complex) {
        ((float2*)out)[p] = make_float2(accre, accim);
    } else {
        out[p] = accre;
    }
}

// ---------------------------------------------------------------------------
extern "C" void kernel_launch(void* const* d_in, const int* in_sizes, int n_in,
                              void* d_out, int out_size, void* d_ws, size_t ws_size,
                              hipStream_t stream)
{
    const float* ir = (const float*)d_in[0];   // [B,640,472,1] float32
    const float* ii = (const float*)d_in[1];   // [B,640,472,1] float32
    const float* kt = (const float*)d_in[2];   // [B,2,K] float32
    float2* tw   = (float2*)d_ws;
    float*  out  = (float*)d_out;

    int write_complex = (out_size >= 2 * BATCH * NK) ? 1 : 0;

    const size_t pb32 = (size_t)GH * GWP * sizeof(float2);       // 9.75 MB
    const size_t pb16 = (size_t)GH * GWP * sizeof(unsigned int); // 4.87 MB
    size_t avail = (ws_size > TW_RESERVE_BYTES) ? ws_size - TW_RESERVE_BYTES : 0;
    int nb = 1;
    if (avail >= 4 * (pb32 + pb16))      nb = 4;
    else if (avail >= 2 * (pb32 + pb16)) nb = 2;

    float2* grid = (float2*)((char*)d_ws + TW_RESERVE_BYTES);
    // bf16 grid right after the nb fp32 slabs (16-B aligned: slab is 16B-mult)
    unsigned int* gridh = (unsigned int*)((char*)grid + (size_t)nb * pb32);

    twiddle_init_kernel<<<5, 256, 0, stream>>>(tw);

    for (int b0 = 0; b0 < BATCH; b0 += nb) {
        fft_row_kernel<<<nb * IH, 256, 0, stream>>>(ir, ii, grid, tw, b0, nb);
        fft_col_kernel<<<nb * (GW / NC), 256, 0, stream>>>(grid, gridh, tw);
        interp_kernel<<<(nb * NK + 255) / 256, 256, 0, stream>>>(kt, gridh, out, b0, nb, write_complex);
    }
}

// Round 11
// 171.079 us; speedup vs baseline: 1.2253x; 1.0624x over previous
//
#include <hip/hip_runtime.h>
#include <math.h>

// Problem constants (match reference)
#define BATCH 4
#define NK    100000
#define IH    640
#define IW    472
#define GH    1280          // oversampled grid rows = 2*IH   (1280 = 20*8*8)
#define GW    944           // oversampled grid cols = 2*IW   (944  = 59*16)
#define GWP   952           // padded row stride: 8 echo cols (window reach <= 951)
#define JW    6             // KB kernel width

// twiddle table layout in ws (units: float2): W_N^t = exp(-2*pi*i*t/N)
#define TW1280_OFF 0
#define TW944_OFF  1280
#define TW_RESERVE_BYTES 32768

#define NC 4                 // columns per fft_col block

static __device__ __forceinline__ float beta_f() {
    return (float)(M_PI * 4.410215414239989);   // pi*sqrt(19.45)
}

// Abramowitz & Stegun I0 approximation (rel err < 2e-7), x >= 0
static __device__ __forceinline__ float i0f_dev(float x) {
    if (x < 3.75f) {
        float t = x * (1.0f / 3.75f);
        t *= t;
        return 1.0f + t*(3.5156229f + t*(3.0899424f + t*(1.2067492f +
               t*(0.2659732f + t*(0.0360768f + t*0.0045813f)))));
    } else {
        float t = 3.75f / x;
        float p = 0.39894228f + t*(0.01328592f + t*(0.00225319f + t*(-0.00157565f +
                  t*(0.00916281f + t*(-0.02057706f + t*(0.02635537f +
                  t*(-0.01647633f + t*0.00392377f)))))));
        return p * expf(x) / sqrtf(x);
    }
}

static __device__ __forceinline__ float2 cmul(float2 a, float2 b) {
    return make_float2(a.x * b.x - a.y * b.y, a.x * b.y + a.y * b.x);
}
static __device__ __forceinline__ float2 cadd(float2 a, float2 b) {
    return make_float2(a.x + b.x, a.y + b.y);
}
static __device__ __forceinline__ float2 csub(float2 a, float2 b) {
    return make_float2(a.x - b.x, a.y - b.y);
}
static __device__ __forceinline__ void cmac(float2& acc, float2 x, float2 w) {
    acc.x += x.x * w.x - x.y * w.y;
    acc.y += x.x * w.y + x.y * w.x;
}

// float -> bf16 bits (round-nearest-even)
static __device__ __forceinline__ unsigned int f2bf(float f) {
    unsigned int u = __float_as_uint(f);
    return (u + 0x7FFFu + ((u >> 16) & 1u)) >> 16;
}

// DFT4: X[k] = sum_n a_n W4^{nk}  (W4 = -i)
static __device__ __forceinline__ void dft4(float2 a0, float2 a1, float2 a2, float2 a3,
                                            float2& o0, float2& o1, float2& o2, float2& o3)
{
    float2 t0 = cadd(a0, a2), t1 = csub(a0, a2);
    float2 t2 = cadd(a1, a3), t3 = csub(a1, a3);
    o0 = cadd(t0, t2);
    o2 = csub(t0, t2);
    float2 nit3 = make_float2(t3.y, -t3.x);   // -i * t3
    o1 = cadd(t1, nit3);
    o3 = csub(t1, nit3);
}

// DFT8: X[k] = sum_n b[n] W8^{nk}
static __device__ __forceinline__ void dft8(const float2* b, float2* X)
{
    float2 e0, e1, e2, e3, o0, o1, o2, o3;
    dft4(b[0], b[2], b[4], b[6], e0, e1, e2, e3);
    dft4(b[1], b[3], b[5], b[7], o0, o1, o2, o3);
    const float S = 0.70710678118654752f;
    float2 m1 = make_float2(S * (o1.x + o1.y), S * (o1.y - o1.x));   // o1*W8^1
    float2 m2 = make_float2(o2.y, -o2.x);                            // o2*(-i)
    float2 m3 = make_float2(S * (o3.y - o3.x), -S * (o3.x + o3.y));  // o3*W8^3
    X[0] = cadd(e0, o0); X[4] = csub(e0, o0);
    X[1] = cadd(e1, m1); X[5] = csub(e1, m1);
    X[2] = cadd(e2, m2); X[6] = csub(e2, m2);
    X[3] = cadd(e3, m3); X[7] = csub(e3, m3);
}

// DFT16: X[k] = sum_n a[n] W16^{nk}  (radix-4 x radix-4, hardcoded twiddles)
static __device__ __forceinline__ void dft16(const float2* a, float2* X)
{
    float2 y[4][4];
    #pragma unroll
    for (int n2 = 0; n2 < 4; ++n2)
        dft4(a[n2], a[4 + n2], a[8 + n2], a[12 + n2],
             y[n2][0], y[n2][1], y[n2][2], y[n2][3]);
    const float C  = 0.70710678118654752f;
    const float c1 = 0.92387953251128676f, s1 = 0.38268343236508977f;
    y[1][1] = cmul(y[1][1], make_float2( c1, -s1));   // W16^1
    y[1][2] = cmul(y[1][2], make_float2(  C,  -C));   // W16^2
    y[1][3] = cmul(y[1][3], make_float2( s1, -c1));   // W16^3
    y[2][1] = cmul(y[2][1], make_float2(  C,  -C));   // W16^2
    y[2][2] = make_float2(y[2][2].y, -y[2][2].x);     // W16^4 = -i
    y[2][3] = cmul(y[2][3], make_float2( -C,  -C));   // W16^6
    y[3][1] = cmul(y[3][1], make_float2( s1, -c1));   // W16^3
    y[3][2] = cmul(y[3][2], make_float2( -C,  -C));   // W16^6
    y[3][3] = cmul(y[3][3], make_float2(-c1,  s1));   // W16^9
    #pragma unroll
    for (int k1 = 0; k1 < 4; ++k1)
        dft4(y[0][k1], y[1][k1], y[2][k1], y[3][k1],
             X[k1], X[k1 + 4], X[k1 + 8], X[k1 + 12]);
}

// ---------------------------------------------------------------------------
// Kernel 0: twiddle tables (5 blocks)
// ---------------------------------------------------------------------------
__global__ __launch_bounds__(256) void twiddle_init_kernel(float2* __restrict__ tw)
{
    int idx = blockIdx.x * 256 + threadIdx.x;
    const double TWO_PI = 6.283185307179586476925286766559;
    if (idx < 1280) {
        double a = -TWO_PI * ((double)idx / 1280.0);
        tw[TW1280_OFF + idx] = make_float2((float)cos(a), (float)sin(a));
    }
    if (idx < 944) {
        double a = -TWO_PI * ((double)idx / 944.0);
        tw[TW944_OFF + idx] = make_float2((float)cos(a), (float)sin(a));
    }
}

// ---------------------------------------------------------------------------
// Kernel 1: FUSED apodize+pad+ifftshift+scale + 944-pt row FFT. 4 rows/block.
// Thread (r,k1): stage-1 59-DFT (30 nonzero taps, shared twiddle recurrence
// across all 16 n2 accumulators) -> W944 fixup (recurrence) -> in-register
// hardcoded DFT-16 -> 16 coalesced global stores. One barrier total.
// ---------------------------------------------------------------------------
__global__ __launch_bounds__(256) void fft_row_kernel(
        const float* __restrict__ ir, const float* __restrict__ ii,
        float2* __restrict__ grid, const float2* __restrict__ twg,
        int b0, int nb)
{
    __shared__ float2 buf[4 * 948];       // stride 948 -> r-groups on disjoint banks

    int blk  = blockIdx.x;                // nb*160 blocks
    int lb   = blk / 160;
    int rblk = (blk % 160) * 4;
    int b    = b0 + lb;
    int tid  = threadIdx.x;
    const float2* tw = twg + TW944_OFF;

    const float B2 = (float)(M_PI * M_PI * 19.45);          // BETA^2
    const float SCALE = (float)(1.0 / 1099.236098591787);   // 1/sqrt(1280*944)

    // load + apodize 4 rows
    for (int item = tid; item < 4 * 944; item += 256) {
        int v  = item % 944;
        int rr = item / 944;
        int ri = rblk + rr;
        int i  = (ri < 320) ? ri + 320 : ri - 320;          // image row
        float2 val = make_float2(0.f, 0.f);
        int j = -1;
        if (v < (GW - IW) / 2) j = v + IW / 2;              // 236..471
        else if (v >= (GW + IW) / 2) j = v - (GW + IW) / 2; // 0..235
        if (j >= 0) {
            float xi = (float)(i - IH / 2) * (1.0f / (float)GH);
            float px = (float)(M_PI * (double)JW) * xi;
            float sxr = sqrtf(B2 - px * px);
            float ax = (float)JW * sinhf(sxr) / sxr;
            float yj = (float)(j - IW / 2) * (1.0f / (float)GW);
            float py = (float)(M_PI * (double)JW) * yj;
            float syr = sqrtf(B2 - py * py);
            float ay = (float)JW * sinhf(syr) / syr;
            float invA = SCALE / (ax * ay);
            size_t src = ((size_t)(b * IH + i)) * IW + j;
            val.x = ir[src] * invA;
            val.y = ii[src] * invA;
        }
        buf[rr * 948 + v] = val;
    }
    __syncthreads();

    if (tid < 236) {
        int r  = tid / 59;
        int k1 = tid % 59;
        int ri = rblk + r;
        int u  = (ri < 320) ? ri : ri + 640;
        float2* rowp = grid + ((size_t)(lb * GH + u)) * GWP;
        const float2* bufr = buf + r * 948;

        float2 acc[16];
        #pragma unroll
        for (int n2 = 0; n2 < 16; ++n2) acc[n2] = make_float2(0.f, 0.f);

        float2 r59 = tw[16 * k1];                     // W59^{k1}
        float2 w = make_float2(1.f, 0.f);
        for (int n1 = 0; n1 < 15; ++n1) {
            const float4* pb = (const float4*)(bufr + (n1 << 4));
            #pragma unroll
            for (int t4 = 0; t4 < 8; ++t4) {
                float4 q = pb[t4];
                cmac(acc[2 * t4],     make_float2(q.x, q.y), w);
                cmac(acc[2 * t4 + 1], make_float2(q.z, q.w), w);
            }
            w = cmul(w, r59);
        }
        w = tw[16 * ((44 * k1) % 59)];                // W59^{44 k1}
        for (int n1 = 44; n1 < 59; ++n1) {
            const float4* pb = (const float4*)(bufr + (n1 << 4));
            #pragma unroll
            for (int t4 = 0; t4 < 8; ++t4) {
                float4 q = pb[t4];
                cmac(acc[2 * t4],     make_float2(q.x, q.y), w);
                cmac(acc[2 * t4 + 1], make_float2(q.z, q.w), w);
            }
            w = cmul(w, r59);
        }

        // inter-stage twiddle W944^{n2 k1} by recurrence
        float2 tstep = tw[k1];
        float2 t = make_float2(1.f, 0.f);
        #pragma unroll
        for (int n2 = 0; n2 < 16; ++n2) {
            acc[n2] = cmul(acc[n2], t);
            t = cmul(t, tstep);
        }

        float2 X[16];
        dft16(acc, X);
        #pragma unroll
        for (int q = 0; q < 16; ++q)
            rowp[k1 + 59 * q] = X[q];                 // coalesced across k1 lanes
    }
}

// ---------------------------------------------------------------------------
// Kernel 2: 1280-pt column FFT (20*8*8), 4 cols/block, fused A+B per thread.
// x buffer holds only the 640 nonzero rows (compacted u'); thread (c,k1,m2)
// computes stage-A (radix-20, zero-skip, shared recurrence across its 8 m
// values), W1280 fixup, hardcoded DFT-8 (m1), W64 fixup -> LDS; stage C is a
// hardcoded DFT-8 (m2) -> packed-bf16 global (+ echo cols for vb<2).
// ---------------------------------------------------------------------------
__global__ __launch_bounds__(256) void fft_col_kernel(
        const float2* __restrict__ grid, unsigned int* __restrict__ gridh,
        const float2* __restrict__ twg)
{
    __shared__ float2 buf[1280 * NC];     // 40960 B (x uses first 640*NC)

    int blk = blockIdx.x;                 // nb * 236
    int lb = blk / (GW / NC);
    int vb = blk % (GW / NC);
    const float2* base = grid + (size_t)lb * GH * GWP + vb * NC;
    unsigned int* baseh = gridh + (size_t)lb * GH * GWP + vb * NC;
    int tid = threadIdx.x;
    const float2* tw = twg + TW1280_OFF;

    // load nonzero rows compacted: u' = u<320 ? u : u-640
    #pragma unroll
    for (int it = 0; it < 10; ++it) {
        int item = it * 256 + tid;
        int c  = item & (NC - 1);
        int up = item >> 2;               // 0..639
        int u  = (up < 320) ? up : up + 640;
        buf[up * NC + c] = base[(size_t)u * GWP + c];
    }
    __syncthreads();

    // stages A+B fused, results held in registers across the barrier
    float2 T[3][8];
    #pragma unroll
    for (int ch = 0; ch < 3; ++ch) {
        int item = ch * 256 + tid;
        if (item < 640) {
            int c  = item & 3;
            int tt = item >> 2;
            int k1 = tt % 20;
            int m2 = tt / 20;             // 0..7

            float2 acc[8];
            #pragma unroll
            for (int j = 0; j < 8; ++j) acc[j] = make_float2(0.f, 0.f);

            float2 r20 = tw[64 * k1];                 // W20^{k1}
            float2 w = make_float2(1.f, 0.f);
            for (int n1 = 0; n1 < 5; ++n1) {          // u' = 64 n1 + 8j + m2
                int ub = (n1 << 6) + m2;
                #pragma unroll
                for (int j = 0; j < 8; ++j)
                    cmac(acc[j], buf[(ub + (j << 3)) * NC + c], w);
                w = cmul(w, r20);
            }
            w = tw[64 * ((15 * k1) % 20)];            // W20^{15 k1}
            for (int n1 = 5; n1 < 10; ++n1) {
                int ub = (n1 << 6) + m2;
                #pragma unroll
                for (int j = 0; j < 8; ++j)
                    cmac(acc[j], buf[(ub + (j << 3)) * NC + c], w);
                w = cmul(w, r20);
            }

            // W1280^{(8j+m2) k1} = W1280^{m2 k1} * (W1280^{8 k1})^j
            float2 tpj = tw[m2 * k1];                 // <=133, no mod needed
            float2 tstep = tw[8 * k1];                // <=152
            #pragma unroll
            for (int j = 0; j < 8; ++j) {
                acc[j] = cmul(acc[j], tpj);
                tpj = cmul(tpj, tstep);
            }

            dft8(acc, T[ch]);                         // DFT over m1 -> k21

            // W64^{m2 k21} = (W1280^{20 m2})^{k21}
            float2 wb = tw[20 * m2];
            float2 v = make_float2(1.f, 0.f);
            #pragma unroll
            for (int k21 = 0; k21 < 8; ++k21) {
                T[ch][k21] = cmul(T[ch][k21], v);
                v = cmul(v, wb);
            }
        }
    }
    __syncthreads();   // all x reads complete

    #pragma unroll
    for (int ch = 0; ch < 3; ++ch) {
        int item = ch * 256 + tid;
        if (item < 640) {
            int c  = item & 3;
            int tt = item >> 2;
            int k1 = tt % 20;
            int m2 = tt / 20;
            #pragma unroll
            for (int k21 = 0; k21 < 8; ++k21)
                buf[(((k21 << 3) + m2) * 20 + k1) * NC + c] = T[ch][k21];
        }
    }
    __syncthreads();

    // stage C: DFT-8 over m2 -> packed bf16 global
    #pragma unroll
    for (int ch = 0; ch < 3; ++ch) {
        int item = ch * 256 + tid;
        if (item < 640) {
            int c   = item & 3;
            int tt  = item >> 2;
            int k1  = tt % 20;
            int k21 = tt / 20;
            float2 bb[8];
            #pragma unroll
            for (int m2 = 0; m2 < 8; ++m2)
                bb[m2] = buf[(((k21 << 3) + m2) * 20 + k1) * NC + c];
            float2 X[8];
            dft8(bb, X);
            #pragma unroll
            for (int k22 = 0; k22 < 8; ++k22) {
                int rrow = k1 + 20 * k21 + 160 * k22;
                unsigned int pk = f2bf(X[k22].x) | (f2bf(X[k22].y) << 16);
                baseh[(size_t)rrow * GWP + c] = pk;
                if (vb < 2) baseh[(size_t)rrow * GWP + GW + c] = pk;  // echo
            }
        }
    }
}

// ---------------------------------------------------------------------------
// Kernel 3: KB interpolation from packed-bf16 grid. One thread per point.
// ---------------------------------------------------------------------------
__global__ __launch_bounds__(256) void interp_kernel(
        const float* __restrict__ ktraj, const unsigned int* __restrict__ gridh,
        float* __restrict__ out, int b0, int nb, int write_complex)
{
    int idx = blockIdx.x * 256 + threadIdx.x;
    if (idx >= nb * NK) return;
    int lb = idx / NK;
    int k  = idx % NK;
    int b  = b0 + lb;

    const float BETA = beta_f();
    float t0 = ktraj[(size_t)(b * 2 + 0) * NK + k] * (float)((double)GH / (2.0 * M_PI));
    float t1 = ktraj[(size_t)(b * 2 + 1) * NK + k] * (float)((double)GW / (2.0 * M_PI));
    int base0 = (int)floorf(t0);
    int base1 = (int)floorf(t1);

    float wx[JW];
    int   ix[JW];
    #pragma unroll
    for (int j = 0; j < JW; ++j) {
        int kx = base0 + j - (JW / 2 - 1);
        float u = t0 - (float)kx;
        float q = u * (1.0f / 3.0f);
        float zz = 1.0f - q * q;
        wx[j] = (zz > 0.f) ? i0f_dev(BETA * sqrtf(zz)) : 0.f;
        int m = kx % GH; if (m < 0) m += GH;
        ix[j] = m;
    }

    int j0u = base1 - 2;
    int a0u = j0u & ~3;
    int aw  = a0u; if (aw < 0) aw += GW;   // [0,940], mult of 4 -> 16B aligned
    float wy12[12];
    #pragma unroll
    for (int t = 0; t < 12; ++t) {
        float u = t1 - (float)(a0u + t);
        float q = u * (1.0f / 3.0f);
        float zz = 1.0f - q * q;
        wy12[t] = (zz > 0.f) ? i0f_dev(BETA * sqrtf(zz)) : 0.f;
    }

    float accre = 0.f, accim = 0.f;
    #pragma unroll
    for (int a = 0; a < JW; ++a) {
        const uint4* p4 = (const uint4*)(gridh + ((size_t)(lb * GH + ix[a])) * GWP + aw);
        uint4 q0 = p4[0];
        uint4 q1 = p4[1];
        uint4 q2 = p4[2];
        float rre = 0.f, rim = 0.f;
        unsigned int qs[12] = {q0.x, q0.y, q0.z, q0.w, q1.x, q1.y, q1.z, q1.w,
                               q2.x, q2.y, q2.z, q2.w};
        #pragma unroll
        for (int t = 0; t < 12; ++t) {
            float gre = __uint_as_float(qs[t] << 16);
            float gim = __uint_as_float(qs[t] & 0xFFFF0000u);
            rre += wy12[t] * gre;
            rim += wy12[t] * gim;
        }
        accre += wx[a] * rre;
        accim += wx[a] * rim;
    }
    size_t p = (size_t)b * NK + k;
    if (write_complex) {
        ((float2*)out)[p] = make_float2(accre, accim);
    } else {
        out[p] = accre;
    }
}

// ---------------------------------------------------------------------------
extern "C" void kernel_launch(void* const* d_in, const int* in_sizes, int n_in,
                              void* d_out, int out_size, void* d_ws, size_t ws_size,
                              hipStream_t stream)
{
    const float* ir = (const float*)d_in[0];   // [B,640,472,1] float32
    const float* ii = (const float*)d_in[1];   // [B,640,472,1] float32
    const float* kt = (const float*)d_in[2];   // [B,2,K] float32
    float2* tw   = (float2*)d_ws;
    float*  out  = (float*)d_out;

    int write_complex = (out_size >= 2 * BATCH * NK) ? 1 : 0;

    const size_t pb32 = (size_t)GH * GWP * sizeof(float2);       // 9.75 MB
    const size_t pb16 = (size_t)GH * GWP * sizeof(unsigned int); // 4.87 MB
    size_t avail = (ws_size > TW_RESERVE_BYTES) ? ws_size - TW_RESERVE_BYTES : 0;
    int nb = 1;
    if (avail >= 4 * (pb32 + pb16))      nb = 4;
    else if (avail >= 2 * (pb32 + pb16)) nb = 2;

    float2* grid = (float2*)((char*)d_ws + TW_RESERVE_BYTES);
    unsigned int* gridh = (unsigned int*)((char*)grid + (size_t)nb * pb32);

    twiddle_init_kernel<<<5, 256, 0, stream>>>(tw);

    for (int b0 = 0; b0 < BATCH; b0 += nb) {
        fft_row_kernel<<<nb * (IH / 4), 256, 0, stream>>>(ir, ii, grid, tw, b0, nb);
        fft_col_kernel<<<nb * (GW / NC), 256, 0, stream>>>(grid, gridh, tw);
        interp_kernel<<<(nb * NK + 255) / 256, 256, 0, stream>>>(kt, gridh, out, b0, nb, write_complex);
    }
}

// Round 12
// 168.428 us; speedup vs baseline: 1.2446x; 1.0157x over previous
//
#include <hip/hip_runtime.h>
#include <math.h>

// Problem constants (match reference)
#define BATCH 4
#define NK    100000
#define IH    640
#define IW    472
#define GH    1280          // oversampled grid rows = 2*IH   (1280 = 20*8*8)
#define GW    944           // oversampled grid cols = 2*IW   (944  = 59*16)
#define GWP   952           // padded row stride: 8 echo cols (window reach <= 951)
#define JW    6             // KB kernel width

// twiddle table layout in ws (units: float2): W_N^t = exp(-2*pi*i*t/N)
#define TW1280_OFF 0
#define TW944_OFF  1280
#define TW_RESERVE_BYTES 32768

#define NC 4                 // columns per fft_col block

static __device__ __forceinline__ float beta_f() {
    return (float)(M_PI * 4.410215414239989);   // pi*sqrt(19.45)
}

// Abramowitz & Stegun I0 approximation (rel err < 2e-7), x >= 0
static __device__ __forceinline__ float i0f_dev(float x) {
    if (x < 3.75f) {
        float t = x * (1.0f / 3.75f);
        t *= t;
        return 1.0f + t*(3.5156229f + t*(3.0899424f + t*(1.2067492f +
               t*(0.2659732f + t*(0.0360768f + t*0.0045813f)))));
    } else {
        float t = 3.75f / x;
        float p = 0.39894228f + t*(0.01328592f + t*(0.00225319f + t*(-0.00157565f +
                  t*(0.00916281f + t*(-0.02057706f + t*(0.02635537f +
                  t*(-0.01647633f + t*0.00392377f)))))));
        return p * expf(x) / sqrtf(x);
    }
}

static __device__ __forceinline__ float2 cmul(float2 a, float2 b) {
    return make_float2(a.x * b.x - a.y * b.y, a.x * b.y + a.y * b.x);
}
static __device__ __forceinline__ float2 cadd(float2 a, float2 b) {
    return make_float2(a.x + b.x, a.y + b.y);
}
static __device__ __forceinline__ float2 csub(float2 a, float2 b) {
    return make_float2(a.x - b.x, a.y - b.y);
}
static __device__ __forceinline__ void cmac(float2& acc, float2 x, float2 w) {
    acc.x += x.x * w.x - x.y * w.y;
    acc.y += x.x * w.y + x.y * w.x;
}

// float -> bf16 bits (round-nearest-even); pack/unpack complex
static __device__ __forceinline__ unsigned int f2bf(float f) {
    unsigned int u = __float_as_uint(f);
    return (u + 0x7FFFu + ((u >> 16) & 1u)) >> 16;
}
static __device__ __forceinline__ unsigned int packbf(float2 v) {
    return f2bf(v.x) | (f2bf(v.y) << 16);
}
static __device__ __forceinline__ float2 unpackbf(unsigned int p) {
    return make_float2(__uint_as_float(p << 16),
                       __uint_as_float(p & 0xFFFF0000u));
}

// DFT4: X[k] = sum_n a_n W4^{nk}  (W4 = -i)
static __device__ __forceinline__ void dft4(float2 a0, float2 a1, float2 a2, float2 a3,
                                            float2& o0, float2& o1, float2& o2, float2& o3)
{
    float2 t0 = cadd(a0, a2), t1 = csub(a0, a2);
    float2 t2 = cadd(a1, a3), t3 = csub(a1, a3);
    o0 = cadd(t0, t2);
    o2 = csub(t0, t2);
    float2 nit3 = make_float2(t3.y, -t3.x);   // -i * t3
    o1 = cadd(t1, nit3);
    o3 = csub(t1, nit3);
}

// DFT8: X[k] = sum_n b[n] W8^{nk}
static __device__ __forceinline__ void dft8(const float2* b, float2* X)
{
    float2 e0, e1, e2, e3, o0, o1, o2, o3;
    dft4(b[0], b[2], b[4], b[6], e0, e1, e2, e3);
    dft4(b[1], b[3], b[5], b[7], o0, o1, o2, o3);
    const float S = 0.70710678118654752f;
    float2 m1 = make_float2(S * (o1.x + o1.y), S * (o1.y - o1.x));   // o1*W8^1
    float2 m2 = make_float2(o2.y, -o2.x);                            // o2*(-i)
    float2 m3 = make_float2(S * (o3.y - o3.x), -S * (o3.x + o3.y));  // o3*W8^3
    X[0] = cadd(e0, o0); X[4] = csub(e0, o0);
    X[1] = cadd(e1, m1); X[5] = csub(e1, m1);
    X[2] = cadd(e2, m2); X[6] = csub(e2, m2);
    X[3] = cadd(e3, m3); X[7] = csub(e3, m3);
}

// DFT16: X[k] = sum_n a[n] W16^{nk}  (radix-4 x radix-4, hardcoded twiddles)
static __device__ __forceinline__ void dft16(const float2* a, float2* X)
{
    float2 y[4][4];
    #pragma unroll
    for (int n2 = 0; n2 < 4; ++n2)
        dft4(a[n2], a[4 + n2], a[8 + n2], a[12 + n2],
             y[n2][0], y[n2][1], y[n2][2], y[n2][3]);
    const float C  = 0.70710678118654752f;
    const float c1 = 0.92387953251128676f, s1 = 0.38268343236508977f;
    y[1][1] = cmul(y[1][1], make_float2( c1, -s1));   // W16^1
    y[1][2] = cmul(y[1][2], make_float2(  C,  -C));   // W16^2
    y[1][3] = cmul(y[1][3], make_float2( s1, -c1));   // W16^3
    y[2][1] = cmul(y[2][1], make_float2(  C,  -C));   // W16^2
    y[2][2] = make_float2(y[2][2].y, -y[2][2].x);     // W16^4 = -i
    y[2][3] = cmul(y[2][3], make_float2( -C,  -C));   // W16^6
    y[3][1] = cmul(y[3][1], make_float2( s1, -c1));   // W16^3
    y[3][2] = cmul(y[3][2], make_float2( -C,  -C));   // W16^6
    y[3][3] = cmul(y[3][3], make_float2(-c1,  s1));   // W16^9
    #pragma unroll
    for (int k1 = 0; k1 < 4; ++k1)
        dft4(y[0][k1], y[1][k1], y[2][k1], y[3][k1],
             X[k1], X[k1 + 4], X[k1 + 8], X[k1 + 12]);
}

// ---------------------------------------------------------------------------
// Kernel 0: twiddle tables (5 blocks)
// ---------------------------------------------------------------------------
__global__ __launch_bounds__(256) void twiddle_init_kernel(float2* __restrict__ tw)
{
    int idx = blockIdx.x * 256 + threadIdx.x;
    const double TWO_PI = 6.283185307179586476925286766559;
    if (idx < 1280) {
        double a = -TWO_PI * ((double)idx / 1280.0);
        tw[TW1280_OFF + idx] = make_float2((float)cos(a), (float)sin(a));
    }
    if (idx < 944) {
        double a = -TWO_PI * ((double)idx / 944.0);
        tw[TW944_OFF + idx] = make_float2((float)cos(a), (float)sin(a));
    }
}

// ---------------------------------------------------------------------------
// Kernel 1: FUSED apodize+pad+ifftshift+scale + 944-pt row FFT. 4 rows/block.
// Output: packed-bf16 grid (uint = re|im<<16).
// ---------------------------------------------------------------------------
__global__ __launch_bounds__(256) void fft_row_kernel(
        const float* __restrict__ ir, const float* __restrict__ ii,
        unsigned int* __restrict__ gridh, const float2* __restrict__ twg,
        int b0, int nb)
{
    __shared__ float2 buf[4 * 948];       // stride 948 -> r-groups on disjoint banks

    int blk  = blockIdx.x;                // nb*160 blocks
    int lb   = blk / 160;
    int rblk = (blk % 160) * 4;
    int b    = b0 + lb;
    int tid  = threadIdx.x;
    const float2* tw = twg + TW944_OFF;

    const float B2 = (float)(M_PI * M_PI * 19.45);          // BETA^2
    const float SCALE = (float)(1.0 / 1099.236098591787);   // 1/sqrt(1280*944)

    // load + apodize 4 rows
    for (int item = tid; item < 4 * 944; item += 256) {
        int v  = item % 944;
        int rr = item / 944;
        int ri = rblk + rr;
        int i  = (ri < 320) ? ri + 320 : ri - 320;          // image row
        float2 val = make_float2(0.f, 0.f);
        int j = -1;
        if (v < (GW - IW) / 2) j = v + IW / 2;              // 236..471
        else if (v >= (GW + IW) / 2) j = v - (GW + IW) / 2; // 0..235
        if (j >= 0) {
            float xi = (float)(i - IH / 2) * (1.0f / (float)GH);
            float px = (float)(M_PI * (double)JW) * xi;
            float sxr = sqrtf(B2 - px * px);
            float ax = (float)JW * sinhf(sxr) / sxr;
            float yj = (float)(j - IW / 2) * (1.0f / (float)GW);
            float py = (float)(M_PI * (double)JW) * yj;
            float syr = sqrtf(B2 - py * py);
            float ay = (float)JW * sinhf(syr) / syr;
            float invA = SCALE / (ax * ay);
            size_t src = ((size_t)(b * IH + i)) * IW + j;
            val.x = ir[src] * invA;
            val.y = ii[src] * invA;
        }
        buf[rr * 948 + v] = val;
    }
    __syncthreads();

    if (tid < 236) {
        int r  = tid / 59;
        int k1 = tid % 59;
        int ri = rblk + r;
        int u  = (ri < 320) ? ri : ri + 640;
        unsigned int* rowp = gridh + ((size_t)(lb * GH + u)) * GWP;
        const float2* bufr = buf + r * 948;

        float2 acc[16];
        #pragma unroll
        for (int n2 = 0; n2 < 16; ++n2) acc[n2] = make_float2(0.f, 0.f);

        float2 r59 = tw[16 * k1];                     // W59^{k1}
        float2 w = make_float2(1.f, 0.f);
        for (int n1 = 0; n1 < 15; ++n1) {
            const float4* pb = (const float4*)(bufr + (n1 << 4));
            #pragma unroll
            for (int t4 = 0; t4 < 8; ++t4) {
                float4 q = pb[t4];
                cmac(acc[2 * t4],     make_float2(q.x, q.y), w);
                cmac(acc[2 * t4 + 1], make_float2(q.z, q.w), w);
            }
            w = cmul(w, r59);
        }
        w = tw[16 * ((44 * k1) % 59)];                // W59^{44 k1}
        for (int n1 = 44; n1 < 59; ++n1) {
            const float4* pb = (const float4*)(bufr + (n1 << 4));
            #pragma unroll
            for (int t4 = 0; t4 < 8; ++t4) {
                float4 q = pb[t4];
                cmac(acc[2 * t4],     make_float2(q.x, q.y), w);
                cmac(acc[2 * t4 + 1], make_float2(q.z, q.w), w);
            }
            w = cmul(w, r59);
        }

        // inter-stage twiddle W944^{n2 k1} by recurrence
        float2 tstep = tw[k1];
        float2 t = make_float2(1.f, 0.f);
        #pragma unroll
        for (int n2 = 0; n2 < 16; ++n2) {
            acc[n2] = cmul(acc[n2], t);
            t = cmul(t, tstep);
        }

        float2 X[16];
        dft16(acc, X);
        #pragma unroll
        for (int q = 0; q < 16; ++q)
            rowp[k1 + 59 * q] = packbf(X[q]);         // coalesced across k1 lanes
    }
}

// ---------------------------------------------------------------------------
// Kernel 2: 1280-pt column FFT (20*8*8), 4 cols/block, fused A+B per thread.
// IN-PLACE on the packed-bf16 grid (block reads all its columns into LDS
// before any write). Compute in fp32. Echo cols [944,952) written by vb<2.
// ---------------------------------------------------------------------------
__global__ __launch_bounds__(256) void fft_col_kernel(
        unsigned int* __restrict__ gridh, const float2* __restrict__ twg)
{
    __shared__ float2 buf[1280 * NC];     // 40960 B (x uses first 640*NC)

    int blk = blockIdx.x;                 // nb * 236
    int lb = blk / (GW / NC);
    int vb = blk % (GW / NC);
    unsigned int* baseh = gridh + (size_t)lb * GH * GWP + vb * NC;
    int tid = threadIdx.x;
    const float2* tw = twg + TW1280_OFF;

    // load nonzero rows compacted: u' = u<320 ? u : u-640
    #pragma unroll
    for (int it = 0; it < 10; ++it) {
        int item = it * 256 + tid;
        int c  = item & (NC - 1);
        int up = item >> 2;               // 0..639
        int u  = (up < 320) ? up : up + 640;
        buf[up * NC + c] = unpackbf(baseh[(size_t)u * GWP + c]);
    }
    __syncthreads();

    // stages A+B fused, results held in registers across the barrier
    float2 T[3][8];
    #pragma unroll
    for (int ch = 0; ch < 3; ++ch) {
        int item = ch * 256 + tid;
        if (item < 640) {
            int c  = item & 3;
            int tt = item >> 2;
            int k1 = tt % 20;
            int m2 = tt / 20;             // 0..7

            float2 acc[8];
            #pragma unroll
            for (int j = 0; j < 8; ++j) acc[j] = make_float2(0.f, 0.f);

            float2 r20 = tw[64 * k1];                 // W20^{k1}
            float2 w = make_float2(1.f, 0.f);
            for (int n1 = 0; n1 < 5; ++n1) {          // u' = 64 n1 + 8j + m2
                int ub = (n1 << 6) + m2;
                #pragma unroll
                for (int j = 0; j < 8; ++j)
                    cmac(acc[j], buf[(ub + (j << 3)) * NC + c], w);
                w = cmul(w, r20);
            }
            w = tw[64 * ((15 * k1) % 20)];            // W20^{15 k1}
            for (int n1 = 5; n1 < 10; ++n1) {
                int ub = (n1 << 6) + m2;
                #pragma unroll
                for (int j = 0; j < 8; ++j)
                    cmac(acc[j], buf[(ub + (j << 3)) * NC + c], w);
                w = cmul(w, r20);
            }

            // W1280^{(8j+m2) k1} = W1280^{m2 k1} * (W1280^{8 k1})^j
            float2 tpj = tw[m2 * k1];                 // <=133, no mod needed
            float2 tstep = tw[8 * k1];                // <=152
            #pragma unroll
            for (int j = 0; j < 8; ++j) {
                acc[j] = cmul(acc[j], tpj);
                tpj = cmul(tpj, tstep);
            }

            dft8(acc, T[ch]);                         // DFT over m1 -> k21

            // W64^{m2 k21} = (W1280^{20 m2})^{k21}
            float2 wb = tw[20 * m2];
            float2 v = make_float2(1.f, 0.f);
            #pragma unroll
            for (int k21 = 0; k21 < 8; ++k21) {
                T[ch][k21] = cmul(T[ch][k21], v);
                v = cmul(v, wb);
            }
        }
    }
    __syncthreads();   // all x reads complete

    #pragma unroll
    for (int ch = 0; ch < 3; ++ch) {
        int item = ch * 256 + tid;
        if (item < 640) {
            int c  = item & 3;
            int tt = item >> 2;
            int k1 = tt % 20;
            int m2 = tt / 20;
            #pragma unroll
            for (int k21 = 0; k21 < 8; ++k21)
                buf[(((k21 << 3) + m2) * 20 + k1) * NC + c] = T[ch][k21];
        }
    }
    __syncthreads();

    // stage C: DFT-8 over m2 -> packed bf16 global (in place)
    #pragma unroll
    for (int ch = 0; ch < 3; ++ch) {
        int item = ch * 256 + tid;
        if (item < 640) {
            int c   = item & 3;
            int tt  = item >> 2;
            int k1  = tt % 20;
            int k21 = tt / 20;
            float2 bb[8];
            #pragma unroll
            for (int m2 = 0; m2 < 8; ++m2)
                bb[m2] = buf[(((k21 << 3) + m2) * 20 + k1) * NC + c];
            float2 X[8];
            dft8(bb, X);
            #pragma unroll
            for (int k22 = 0; k22 < 8; ++k22) {
                int rrow = k1 + 20 * k21 + 160 * k22;
                unsigned int pk = packbf(X[k22]);
                baseh[(size_t)rrow * GWP + c] = pk;
                if (vb < 2) baseh[(size_t)rrow * GWP + GW + c] = pk;  // echo
            }
        }
    }
}

// ---------------------------------------------------------------------------
// Kernel 3: KB interpolation from packed-bf16 grid. One thread per point.
// swizzle=1 (nb==4): batch lb mapped to XCDs {2lb,2lb+1} via blockIdx%8 so
// each XCD's 4 MB L2 caches (most of) one 4.87 MB batch slab.
// Third window load issued only when (j0u&3)==3 (taps 8..11 else zero-weight).
// ---------------------------------------------------------------------------
__global__ __launch_bounds__(256) void interp_kernel(
        const float* __restrict__ ktraj, const unsigned int* __restrict__ gridh,
        float* __restrict__ out, int b0, int nb, int write_complex, int swizzle)
{
    int lb, k;
    if (swizzle) {
        int g = blockIdx.x;               // 1568 blocks: 8 XCD slots x 196
        int xcd = g & 7;
        lb = xcd >> 1;
        int slot = ((g >> 3) << 1) | (g & 1);   // 0..391 per batch
        int p = slot * 256 + threadIdx.x;
        if (p >= NK) return;
        k = p;
    } else {
        int idx = blockIdx.x * 256 + threadIdx.x;
        if (idx >= nb * NK) return;
        lb = idx / NK;
        k  = idx % NK;
    }
    int b = b0 + lb;

    const float BETA = beta_f();
    float t0 = ktraj[(size_t)(b * 2 + 0) * NK + k] * (float)((double)GH / (2.0 * M_PI));
    float t1 = ktraj[(size_t)(b * 2 + 1) * NK + k] * (float)((double)GW / (2.0 * M_PI));
    int base0 = (int)floorf(t0);
    int base1 = (int)floorf(t1);

    float wx[JW];
    int   ix[JW];
    #pragma unroll
    for (int j = 0; j < JW; ++j) {
        int kx = base0 + j - (JW / 2 - 1);
        float u = t0 - (float)kx;
        float q = u * (1.0f / 3.0f);
        float zz = 1.0f - q * q;
        wx[j] = (zz > 0.f) ? i0f_dev(BETA * sqrtf(zz)) : 0.f;
        int m = kx % GH; if (m < 0) m += GH;
        ix[j] = m;
    }

    int j0u = base1 - 2;
    int d   = j0u & 3;
    int a0u = j0u & ~3;
    int aw  = a0u; if (aw < 0) aw += GW;   // [0,940], mult of 4 -> 16B aligned
    float wy12[12];
    #pragma unroll
    for (int t = 0; t < 12; ++t) {
        float u = t1 - (float)(a0u + t);
        float q = u * (1.0f / 3.0f);
        float zz = 1.0f - q * q;
        wy12[t] = (zz > 0.f) ? i0f_dev(BETA * sqrtf(zz)) : 0.f;
    }
    bool need3 = (d == 3);

    float accre = 0.f, accim = 0.f;
    #pragma unroll
    for (int a = 0; a < JW; ++a) {
        const uint4* p4 = (const uint4*)(gridh + ((size_t)(lb * GH + ix[a])) * GWP + aw);
        uint4 q0 = p4[0];
        uint4 q1 = p4[1];
        uint4 q2 = need3 ? p4[2] : make_uint4(0u, 0u, 0u, 0u);
        float rre = 0.f, rim = 0.f;
        unsigned int qs[12] = {q0.x, q0.y, q0.z, q0.w, q1.x, q1.y, q1.z, q1.w,
                               q2.x, q2.y, q2.z, q2.w};
        #pragma unroll
        for (int t = 0; t < 12; ++t) {
            float2 g2 = unpackbf(qs[t]);
            rre += wy12[t] * g2.x;
            rim += wy12[t] * g2.y;
        }
        accre += wx[a] * rre;
        accim += wx[a] * rim;
    }
    size_t p = (size_t)b * NK + k;
    if (write_complex) {
        ((float2*)out)[p] = make_float2(accre, accim);
    } else {
        out[p] = accre;
    }
}

// ---------------------------------------------------------------------------
extern "C" void kernel_launch(void* const* d_in, const int* in_sizes, int n_in,
                              void* d_out, int out_size, void* d_ws, size_t ws_size,
                              hipStream_t stream)
{
    const float* ir = (const float*)d_in[0];   // [B,640,472,1] float32
    const float* ii = (const float*)d_in[1];   // [B,640,472,1] float32
    const float* kt = (const float*)d_in[2];   // [B,2,K] float32
    float2* tw   = (float2*)d_ws;
    float*  out  = (float*)d_out;

    int write_complex = (out_size >= 2 * BATCH * NK) ? 1 : 0;

    const size_t pb16 = (size_t)GH * GWP * sizeof(unsigned int); // 4.87 MB
    size_t avail = (ws_size > TW_RESERVE_BYTES) ? ws_size - TW_RESERVE_BYTES : 0;
    int nb = 1;
    if (avail >= 4 * pb16)      nb = 4;
    else if (avail >= 2 * pb16) nb = 2;

    unsigned int* gridh = (unsigned int*)((char*)d_ws + TW_RESERVE_BYTES);

    twiddle_init_kernel<<<5, 256, 0, stream>>>(tw);

    for (int b0 = 0; b0 < BATCH; b0 += nb) {
        fft_row_kernel<<<nb * (IH / 4), 256, 0, stream>>>(ir, ii, gridh, tw, b0, nb);
        fft_col_kernel<<<nb * (GW / NC), 256, 0, stream>>>(gridh, tw);
        if (nb == 4) {
            interp_kernel<<<1568, 256, 0, stream>>>(kt, gridh, out, b0, nb, write_complex, 1);
        } else {
            interp_kernel<<<(nb * NK + 255) / 256, 256, 0, stream>>>(kt, gridh, out, b0, nb, write_complex, 0);
        }
    }
}

// Round 13
// 162.031 us; speedup vs baseline: 1.2938x; 1.0395x over previous
//
#include <hip/hip_runtime.h>
#include <math.h>

// Problem constants (match reference)
#define BATCH 4
#define NK    100000
#define IH    640
#define IW    472
#define GH    1280          // oversampled grid rows = 2*IH   (1280 = 20*8*8)
#define GW    944           // oversampled grid cols = 2*IW   (944  = 59*16)
#define GWP   952           // padded row stride: 8 echo cols (window reach <= 951)
#define JW    6             // KB kernel width

// twiddle table layout in ws (units: float2): W_N^t = exp(-2*pi*i*t/N)
#define TW1280_OFF 0
#define TW944_OFF  1280
#define TW_RESERVE_BYTES 32768

#define NC 4                 // columns per fft_col block

typedef float v2f __attribute__((ext_vector_type(2)));
typedef float v4f __attribute__((ext_vector_type(4)));

static __device__ __forceinline__ float beta_f() {
    return (float)(M_PI * 4.410215414239989);   // pi*sqrt(19.45)
}

// Abramowitz & Stegun I0 approximation (rel err < 2e-7), x >= 0
static __device__ __forceinline__ float i0f_dev(float x) {
    if (x < 3.75f) {
        float t = x * (1.0f / 3.75f);
        t *= t;
        return 1.0f + t*(3.5156229f + t*(3.0899424f + t*(1.2067492f +
               t*(0.2659732f + t*(0.0360768f + t*0.0045813f)))));
    } else {
        float t = 3.75f / x;
        float p = 0.39894228f + t*(0.01328592f + t*(0.00225319f + t*(-0.00157565f +
                  t*(0.00916281f + t*(-0.02057706f + t*(0.02635537f +
                  t*(-0.01647633f + t*0.00392377f)))))));
        return p * expf(x) / sqrtf(x);
    }
}

// ---- packed complex helpers (complex = v2f (re,im); ops lower to v_pk_*_f32)
static __device__ __forceinline__ v2f perp(v2f w) {            // (-w.y, w.x)
    return (v2f){-w.y, w.x};
}
// x * w with wp = perp(w) precomputed: 2 pk_fma
static __device__ __forceinline__ v2f cmulp(v2f x, v2f w, v2f wp) {
    v2f xr = __builtin_shufflevector(x, x, 0, 0);
    v2f xi = __builtin_shufflevector(x, x, 1, 1);
    return xr * w + xi * wp;
}
static __device__ __forceinline__ v2f cmul(v2f a, v2f b) {
    return cmulp(a, b, perp(b));
}
static __device__ __forceinline__ void cmacp(v2f& acc, v2f x, v2f w, v2f wp) {
    v2f xr = __builtin_shufflevector(x, x, 0, 0);
    v2f xi = __builtin_shufflevector(x, x, 1, 1);
    acc += xr * w;
    acc += xi * wp;
}

// float -> bf16 bits (round-nearest-even); pack/unpack complex
static __device__ __forceinline__ unsigned int f2bf(float f) {
    unsigned int u = __float_as_uint(f);
    return (u + 0x7FFFu + ((u >> 16) & 1u)) >> 16;
}
static __device__ __forceinline__ unsigned int packbf(v2f v) {
    return f2bf(v.x) | (f2bf(v.y) << 16);
}
static __device__ __forceinline__ v2f unpackbf(unsigned int p) {
    return (v2f){__uint_as_float(p << 16), __uint_as_float(p & 0xFFFF0000u)};
}

// DFT4: X[k] = sum_n a_n W4^{nk}  (W4 = -i) — pk add/sub
static __device__ __forceinline__ void dft4(v2f a0, v2f a1, v2f a2, v2f a3,
                                            v2f& o0, v2f& o1, v2f& o2, v2f& o3)
{
    v2f t0 = a0 + a2, t1 = a0 - a2;
    v2f t2 = a1 + a3, t3 = a1 - a3;
    o0 = t0 + t2;
    o2 = t0 - t2;
    v2f nit3 = (v2f){t3.y, -t3.x};   // -i * t3
    o1 = t1 + nit3;
    o3 = t1 - nit3;
}

// DFT8: X[k] = sum_n b[n] W8^{nk}
static __device__ __forceinline__ void dft8(const v2f* b, v2f* X)
{
    v2f e0, e1, e2, e3, o0, o1, o2, o3;
    dft4(b[0], b[2], b[4], b[6], e0, e1, e2, e3);
    dft4(b[1], b[3], b[5], b[7], o0, o1, o2, o3);
    const float C = 0.70710678118654752f;
    v2f m1 = cmulp(o1, (v2f){ C, -C}, (v2f){C,  C});   // o1*W8^1
    v2f m2 = (v2f){o2.y, -o2.x};                       // o2*(-i)
    v2f m3 = cmulp(o3, (v2f){-C, -C}, (v2f){C, -C});   // o3*W8^3
    X[0] = e0 + o0; X[4] = e0 - o0;
    X[1] = e1 + m1; X[5] = e1 - m1;
    X[2] = e2 + m2; X[6] = e2 - m2;
    X[3] = e3 + m3; X[7] = e3 - m3;
}

// DFT16: radix-4 x radix-4, constant twiddles with precomputed perps
static __device__ __forceinline__ void dft16(const v2f* a, v2f* X)
{
    v2f y[4][4];
    #pragma unroll
    for (int n2 = 0; n2 < 4; ++n2)
        dft4(a[n2], a[4 + n2], a[8 + n2], a[12 + n2],
             y[n2][0], y[n2][1], y[n2][2], y[n2][3]);
    const float C  = 0.70710678118654752f;
    const float c1 = 0.92387953251128676f, s1 = 0.38268343236508977f;
    y[1][1] = cmulp(y[1][1], (v2f){ c1, -s1}, (v2f){ s1,  c1});  // W16^1
    y[1][2] = cmulp(y[1][2], (v2f){  C,  -C}, (v2f){  C,   C});  // W16^2
    y[1][3] = cmulp(y[1][3], (v2f){ s1, -c1}, (v2f){ c1,  s1});  // W16^3
    y[2][1] = cmulp(y[2][1], (v2f){  C,  -C}, (v2f){  C,   C});  // W16^2
    y[2][2] = (v2f){y[2][2].y, -y[2][2].x};                      // W16^4 = -i
    y[2][3] = cmulp(y[2][3], (v2f){ -C,  -C}, (v2f){  C,  -C});  // W16^6
    y[3][1] = cmulp(y[3][1], (v2f){ s1, -c1}, (v2f){ c1,  s1});  // W16^3
    y[3][2] = cmulp(y[3][2], (v2f){ -C,  -C}, (v2f){  C,  -C});  // W16^6
    y[3][3] = cmulp(y[3][3], (v2f){-c1,  s1}, (v2f){-s1, -c1});  // W16^9
    #pragma unroll
    for (int k1 = 0; k1 < 4; ++k1)
        dft4(y[0][k1], y[1][k1], y[2][k1], y[3][k1],
             X[k1], X[k1 + 4], X[k1 + 8], X[k1 + 12]);
}

// ---------------------------------------------------------------------------
// Kernel 0: twiddle tables (5 blocks)
// ---------------------------------------------------------------------------
__global__ __launch_bounds__(256) void twiddle_init_kernel(float2* __restrict__ tw)
{
    int idx = blockIdx.x * 256 + threadIdx.x;
    const double TWO_PI = 6.283185307179586476925286766559;
    if (idx < 1280) {
        double a = -TWO_PI * ((double)idx / 1280.0);
        tw[TW1280_OFF + idx] = make_float2((float)cos(a), (float)sin(a));
    }
    if (idx < 944) {
        double a = -TWO_PI * ((double)idx / 944.0);
        tw[TW944_OFF + idx] = make_float2((float)cos(a), (float)sin(a));
    }
}

// ---------------------------------------------------------------------------
// Kernel 1: FUSED apodize+pad+ifftshift+scale + 944-pt row FFT. 4 rows/block.
// Output: packed-bf16 grid (uint = re|im<<16). All complex math packed (v2f).
// ---------------------------------------------------------------------------
__global__ __launch_bounds__(256) void fft_row_kernel(
        const float* __restrict__ ir, const float* __restrict__ ii,
        unsigned int* __restrict__ gridh, const v2f* __restrict__ twg,
        int b0, int nb)
{
    __shared__ v2f buf[4 * 948];          // stride 948 -> r-groups on disjoint banks

    int blk  = blockIdx.x;                // nb*160 blocks
    int lb   = blk / 160;
    int rblk = (blk % 160) * 4;
    int b    = b0 + lb;
    int tid  = threadIdx.x;
    const v2f* tw = twg + TW944_OFF;

    const float B2 = (float)(M_PI * M_PI * 19.45);          // BETA^2
    const float SCALE = (float)(1.0 / 1099.236098591787);   // 1/sqrt(1280*944)

    // load + apodize 4 rows
    for (int item = tid; item < 4 * 944; item += 256) {
        int v  = item % 944;
        int rr = item / 944;
        int ri = rblk + rr;
        int i  = (ri < 320) ? ri + 320 : ri - 320;          // image row
        v2f val = (v2f){0.f, 0.f};
        int j = -1;
        if (v < (GW - IW) / 2) j = v + IW / 2;              // 236..471
        else if (v >= (GW + IW) / 2) j = v - (GW + IW) / 2; // 0..235
        if (j >= 0) {
            float xi = (float)(i - IH / 2) * (1.0f / (float)GH);
            float px = (float)(M_PI * (double)JW) * xi;
            float sxr = sqrtf(B2 - px * px);
            float ax = (float)JW * sinhf(sxr) / sxr;
            float yj = (float)(j - IW / 2) * (1.0f / (float)GW);
            float py = (float)(M_PI * (double)JW) * yj;
            float syr = sqrtf(B2 - py * py);
            float ay = (float)JW * sinhf(syr) / syr;
            float invA = SCALE / (ax * ay);
            size_t src = ((size_t)(b * IH + i)) * IW + j;
            val.x = ir[src] * invA;
            val.y = ii[src] * invA;
        }
        buf[rr * 948 + v] = val;
    }
    __syncthreads();

    if (tid < 236) {
        int r  = tid / 59;
        int k1 = tid % 59;
        int ri = rblk + r;
        int u  = (ri < 320) ? ri : ri + 640;
        unsigned int* rowp = gridh + ((size_t)(lb * GH + u)) * GWP;
        const v2f* bufr = buf + r * 948;

        v2f acc[16];
        #pragma unroll
        for (int n2 = 0; n2 < 16; ++n2) acc[n2] = (v2f){0.f, 0.f};

        v2f r59 = tw[16 * k1];                        // W59^{k1}
        v2f r59p = perp(r59);
        v2f w = (v2f){1.f, 0.f};
        v2f wp = (v2f){0.f, 1.f};
        for (int n1 = 0; n1 < 15; ++n1) {
            const v4f* pb = (const v4f*)(bufr + (n1 << 4));
            #pragma unroll
            for (int t4 = 0; t4 < 8; ++t4) {
                v4f q = pb[t4];
                v2f c0 = __builtin_shufflevector(q, q, 0, 1);
                v2f c1 = __builtin_shufflevector(q, q, 2, 3);
                cmacp(acc[2 * t4],     c0, w, wp);
                cmacp(acc[2 * t4 + 1], c1, w, wp);
            }
            w = cmulp(w, r59, r59p);
            wp = perp(w);
        }
        w = tw[16 * ((44 * k1) % 59)];                // W59^{44 k1}
        wp = perp(w);
        for (int n1 = 44; n1 < 59; ++n1) {
            const v4f* pb = (const v4f*)(bufr + (n1 << 4));
            #pragma unroll
            for (int t4 = 0; t4 < 8; ++t4) {
                v4f q = pb[t4];
                v2f c0 = __builtin_shufflevector(q, q, 0, 1);
                v2f c1 = __builtin_shufflevector(q, q, 2, 3);
                cmacp(acc[2 * t4],     c0, w, wp);
                cmacp(acc[2 * t4 + 1], c1, w, wp);
            }
            w = cmulp(w, r59, r59p);
            wp = perp(w);
        }

        // inter-stage twiddle W944^{n2 k1} by recurrence
        v2f tstep = tw[k1];
        v2f tstepp = perp(tstep);
        v2f t = (v2f){1.f, 0.f};
        v2f tp = (v2f){0.f, 1.f};
        #pragma unroll
        for (int n2 = 0; n2 < 16; ++n2) {
            acc[n2] = cmulp(acc[n2], t, tp);
            t = cmulp(t, tstep, tstepp);
            tp = perp(t);
        }

        v2f X[16];
        dft16(acc, X);
        #pragma unroll
        for (int q = 0; q < 16; ++q)
            rowp[k1 + 59 * q] = packbf(X[q]);         // coalesced across k1 lanes
    }
}

// ---------------------------------------------------------------------------
// Kernel 2: 1280-pt column FFT (20*8*8), 4 cols/block, fused A+B per thread.
// IN-PLACE on the packed-bf16 grid. Packed (v2f) complex math throughout.
// ---------------------------------------------------------------------------
__global__ __launch_bounds__(256) void fft_col_kernel(
        unsigned int* __restrict__ gridh, const v2f* __restrict__ twg)
{
    __shared__ v2f buf[1280 * NC];        // 40960 B (x uses first 640*NC)

    int blk = blockIdx.x;                 // nb * 236
    int lb = blk / (GW / NC);
    int vb = blk % (GW / NC);
    unsigned int* baseh = gridh + (size_t)lb * GH * GWP + vb * NC;
    int tid = threadIdx.x;
    const v2f* tw = twg + TW1280_OFF;

    // load nonzero rows compacted: u' = u<320 ? u : u-640
    #pragma unroll
    for (int it = 0; it < 10; ++it) {
        int item = it * 256 + tid;
        int c  = item & (NC - 1);
        int up = item >> 2;               // 0..639
        int u  = (up < 320) ? up : up + 640;
        buf[up * NC + c] = unpackbf(baseh[(size_t)u * GWP + c]);
    }
    __syncthreads();

    // stages A+B fused, results held in registers across the barrier
    v2f T[3][8];
    #pragma unroll
    for (int ch = 0; ch < 3; ++ch) {
        int item = ch * 256 + tid;
        if (item < 640) {
            int c  = item & 3;
            int tt = item >> 2;
            int k1 = tt % 20;
            int m2 = tt / 20;             // 0..7

            v2f acc[8];
            #pragma unroll
            for (int j = 0; j < 8; ++j) acc[j] = (v2f){0.f, 0.f};

            v2f r20 = tw[64 * k1];                    // W20^{k1}
            v2f r20p = perp(r20);
            v2f w = (v2f){1.f, 0.f};
            v2f wp = (v2f){0.f, 1.f};
            for (int n1 = 0; n1 < 5; ++n1) {          // u' = 64 n1 + 8j + m2
                int ub = (n1 << 6) + m2;
                #pragma unroll
                for (int j = 0; j < 8; ++j)
                    cmacp(acc[j], buf[(ub + (j << 3)) * NC + c], w, wp);
                w = cmulp(w, r20, r20p);
                wp = perp(w);
            }
            w = tw[64 * ((15 * k1) % 20)];            // W20^{15 k1}
            wp = perp(w);
            for (int n1 = 5; n1 < 10; ++n1) {
                int ub = (n1 << 6) + m2;
                #pragma unroll
                for (int j = 0; j < 8; ++j)
                    cmacp(acc[j], buf[(ub + (j << 3)) * NC + c], w, wp);
                w = cmulp(w, r20, r20p);
                wp = perp(w);
            }

            // W1280^{(8j+m2) k1} = W1280^{m2 k1} * (W1280^{8 k1})^j
            v2f tpj = tw[m2 * k1];                    // <=133, no mod needed
            v2f tstep = tw[8 * k1];                   // <=152
            v2f tstepp = perp(tstep);
            #pragma unroll
            for (int j = 0; j < 8; ++j) {
                acc[j] = cmulp(acc[j], tpj, perp(tpj));
                tpj = cmulp(tpj, tstep, tstepp);
            }

            dft8(acc, T[ch]);                         // DFT over m1 -> k21

            // W64^{m2 k21} = (W1280^{20 m2})^{k21}
            v2f wb = tw[20 * m2];
            v2f wbp = perp(wb);
            v2f v = (v2f){1.f, 0.f};
            #pragma unroll
            for (int k21 = 0; k21 < 8; ++k21) {
                T[ch][k21] = cmulp(T[ch][k21], v, perp(v));
                v = cmulp(v, wb, wbp);
            }
        }
    }
    __syncthreads();   // all x reads complete

    #pragma unroll
    for (int ch = 0; ch < 3; ++ch) {
        int item = ch * 256 + tid;
        if (item < 640) {
            int c  = item & 3;
            int tt = item >> 2;
            int k1 = tt % 20;
            int m2 = tt / 20;
            #pragma unroll
            for (int k21 = 0; k21 < 8; ++k21)
                buf[(((k21 << 3) + m2) * 20 + k1) * NC + c] = T[ch][k21];
        }
    }
    __syncthreads();

    // stage C: DFT-8 over m2 -> packed bf16 global (in place)
    #pragma unroll
    for (int ch = 0; ch < 3; ++ch) {
        int item = ch * 256 + tid;
        if (item < 640) {
            int c   = item & 3;
            int tt  = item >> 2;
            int k1  = tt % 20;
            int k21 = tt / 20;
            v2f bb[8];
            #pragma unroll
            for (int m2 = 0; m2 < 8; ++m2)
                bb[m2] = buf[(((k21 << 3) + m2) * 20 + k1) * NC + c];
            v2f X[8];
            dft8(bb, X);
            #pragma unroll
            for (int k22 = 0; k22 < 8; ++k22) {
                int rrow = k1 + 20 * k21 + 160 * k22;
                unsigned int pk = packbf(X[k22]);
                baseh[(size_t)rrow * GWP + c] = pk;
                if (vb < 2) baseh[(size_t)rrow * GWP + GW + c] = pk;  // echo
            }
        }
    }
}

// ---------------------------------------------------------------------------
// Kernel 3: KB interpolation from packed-bf16 grid. One thread per point.
// Tap MACs packed: acc(v2f) += w * (re,im) -> one v_pk_fma_f32 per tap.
// ---------------------------------------------------------------------------
__global__ __launch_bounds__(256) void interp_kernel(
        const float* __restrict__ ktraj, const unsigned int* __restrict__ gridh,
        float* __restrict__ out, int b0, int nb, int write_complex, int swizzle)
{
    int lb, k;
    if (swizzle) {
        int g = blockIdx.x;               // 1568 blocks: 8 XCD slots x 196
        int xcd = g & 7;
        lb = xcd >> 1;
        int slot = ((g >> 3) << 1) | (g & 1);   // 0..391 per batch
        int p = slot * 256 + threadIdx.x;
        if (p >= NK) return;
        k = p;
    } else {
        int idx = blockIdx.x * 256 + threadIdx.x;
        if (idx >= nb * NK) return;
        lb = idx / NK;
        k  = idx % NK;
    }
    int b = b0 + lb;

    const float BETA = beta_f();
    float t0 = ktraj[(size_t)(b * 2 + 0) * NK + k] * (float)((double)GH / (2.0 * M_PI));
    float t1 = ktraj[(size_t)(b * 2 + 1) * NK + k] * (float)((double)GW / (2.0 * M_PI));
    int base0 = (int)floorf(t0);
    int base1 = (int)floorf(t1);

    float wx[JW];
    int   ix[JW];
    #pragma unroll
    for (int j = 0; j < JW; ++j) {
        int kx = base0 + j - (JW / 2 - 1);
        float u = t0 - (float)kx;
        float q = u * (1.0f / 3.0f);
        float zz = 1.0f - q * q;
        wx[j] = (zz > 0.f) ? i0f_dev(BETA * sqrtf(zz)) : 0.f;
        int m = kx % GH; if (m < 0) m += GH;
        ix[j] = m;
    }

    int j0u = base1 - 2;
    int d   = j0u & 3;
    int a0u = j0u & ~3;
    int aw  = a0u; if (aw < 0) aw += GW;   // [0,940], mult of 4 -> 16B aligned
    float wy12[12];
    #pragma unroll
    for (int t = 0; t < 12; ++t) {
        float u = t1 - (float)(a0u + t);
        float q = u * (1.0f / 3.0f);
        float zz = 1.0f - q * q;
        wy12[t] = (zz > 0.f) ? i0f_dev(BETA * sqrtf(zz)) : 0.f;
    }
    bool need3 = (d == 3);

    v2f acc = (v2f){0.f, 0.f};
    #pragma unroll
    for (int a = 0; a < JW; ++a) {
        const uint4* p4 = (const uint4*)(gridh + ((size_t)(lb * GH + ix[a])) * GWP + aw);
        uint4 q0 = p4[0];
        uint4 q1 = p4[1];
        uint4 q2 = need3 ? p4[2] : make_uint4(0u, 0u, 0u, 0u);
        unsigned int qs[12] = {q0.x, q0.y, q0.z, q0.w, q1.x, q1.y, q1.z, q1.w,
                               q2.x, q2.y, q2.z, q2.w};
        v2f rr = (v2f){0.f, 0.f};
        #pragma unroll
        for (int t = 0; t < 12; ++t)
            rr += wy12[t] * unpackbf(qs[t]);          // 1 pk_fma per tap
        acc += wx[a] * rr;
    }
    size_t p = (size_t)b * NK + k;
    if (write_complex) {
        ((float2*)out)[p] = make_float2(acc.x, acc.y);
    } else {
        out[p] = acc.x;
    }
}

// ---------------------------------------------------------------------------
extern "C" void kernel_launch(void* const* d_in, const int* in_sizes, int n_in,
                              void* d_out, int out_size, void* d_ws, size_t ws_size,
                              hipStream_t stream)
{
    const float* ir = (const float*)d_in[0];   // [B,640,472,1] float32
    const float* ii = (const float*)d_in[1];   // [B,640,472,1] float32
    const float* kt = (const float*)d_in[2];   // [B,2,K] float32
    float2* tw   = (float2*)d_ws;
    float*  out  = (float*)d_out;

    int write_complex = (out_size >= 2 * BATCH * NK) ? 1 : 0;

    const size_t pb16 = (size_t)GH * GWP * sizeof(unsigned int); // 4.87 MB
    size_t avail = (ws_size > TW_RESERVE_BYTES) ? ws_size - TW_RESERVE_BYTES : 0;
    int nb = 1;
    if (avail >= 4 * pb16)      nb = 4;
    else if (avail >= 2 * pb16) nb = 2;

    unsigned int* gridh = (unsigned int*)((char*)d_ws + TW_RESERVE_BYTES);

    twiddle_init_kernel<<<5, 256, 0, stream>>>(tw);

    for (int b0 = 0; b0 < BATCH; b0 += nb) {
        fft_row_kernel<<<nb * (IH / 4), 256, 0, stream>>>(ir, ii, gridh, (const v2f*)tw, b0, nb);
        fft_col_kernel<<<nb * (GW / NC), 256, 0, stream>>>(gridh, (const v2f*)tw);
        if (nb == 4) {
            interp_kernel<<<1568, 256, 0, stream>>>(kt, gridh, out, b0, nb, write_complex, 1);
        } else {
            interp_kernel<<<(nb * NK + 255) / 256, 256, 0, stream>>>(kt, gridh, out, b0, nb, write_complex, 0);
        }
    }
}

// Round 14
// 161.471 us; speedup vs baseline: 1.2982x; 1.0035x over previous
//
#include <hip/hip_runtime.h>
#include <math.h>

// Problem constants (match reference)
#define BATCH 4
#define NK    100000
#define IH    640
#define IW    472
#define GH    1280          // oversampled grid rows = 2*IH   (1280 = 20*8*8)
#define GW    944           // oversampled grid cols = 2*IW   (944  = 59*16)
#define GWP   952           // padded row stride: 8 echo cols (window reach <= 951)
#define JW    6             // KB kernel width

// ws layout (bytes): [tw: 2224 v2f][kb table: 4097 f][apodx: 640 f][apody: 472 f]
#define TW1280_OFF 0
#define TW944_OFF  1280
#define KB_OFF_B   18432
#define AX_OFF_B   34944
#define AY_OFF_B   37504
#define TW_RESERVE_BYTES 65536

#define KBN 4095             // table scale: idx = z*KBN, entries 0..4096

#define NC 4                 // columns per fft_col block

typedef float v2f __attribute__((ext_vector_type(2)));
typedef float v4f __attribute__((ext_vector_type(4)));

static __device__ __forceinline__ float beta_f() {
    return (float)(M_PI * 4.410215414239989);   // pi*sqrt(19.45)
}

// Abramowitz & Stegun I0 approximation (rel err < 2e-7), x >= 0
static __device__ __forceinline__ float i0f_dev(float x) {
    if (x < 3.75f) {
        float t = x * (1.0f / 3.75f);
        t *= t;
        return 1.0f + t*(3.5156229f + t*(3.0899424f + t*(1.2067492f +
               t*(0.2659732f + t*(0.0360768f + t*0.0045813f)))));
    } else {
        float t = 3.75f / x;
        float p = 0.39894228f + t*(0.01328592f + t*(0.00225319f + t*(-0.00157565f +
                  t*(0.00916281f + t*(-0.02057706f + t*(0.02635537f +
                  t*(-0.01647633f + t*0.00392377f)))))));
        return p * expf(x) / sqrtf(x);
    }
}

// ---- packed complex helpers (complex = v2f (re,im); ops lower to v_pk_*_f32)
static __device__ __forceinline__ v2f perp(v2f w) { return (v2f){-w.y, w.x}; }
static __device__ __forceinline__ v2f cmulp(v2f x, v2f w, v2f wp) {
    v2f xr = __builtin_shufflevector(x, x, 0, 0);
    v2f xi = __builtin_shufflevector(x, x, 1, 1);
    return xr * w + xi * wp;
}
static __device__ __forceinline__ v2f cmul(v2f a, v2f b) { return cmulp(a, b, perp(b)); }
static __device__ __forceinline__ void cmacp(v2f& acc, v2f x, v2f w, v2f wp) {
    v2f xr = __builtin_shufflevector(x, x, 0, 0);
    v2f xi = __builtin_shufflevector(x, x, 1, 1);
    acc += xr * w;
    acc += xi * wp;
}

// float -> bf16 bits (round-nearest-even); pack/unpack complex
static __device__ __forceinline__ unsigned int f2bf(float f) {
    unsigned int u = __float_as_uint(f);
    return (u + 0x7FFFu + ((u >> 16) & 1u)) >> 16;
}
static __device__ __forceinline__ unsigned int packbf(v2f v) {
    return f2bf(v.x) | (f2bf(v.y) << 16);
}
static __device__ __forceinline__ v2f unpackbf(unsigned int p) {
    return (v2f){__uint_as_float(p << 16), __uint_as_float(p & 0xFFFF0000u)};
}

// DFT4 (W4 = -i)
static __device__ __forceinline__ void dft4(v2f a0, v2f a1, v2f a2, v2f a3,
                                            v2f& o0, v2f& o1, v2f& o2, v2f& o3)
{
    v2f t0 = a0 + a2, t1 = a0 - a2;
    v2f t2 = a1 + a3, t3 = a1 - a3;
    o0 = t0 + t2;
    o2 = t0 - t2;
    v2f nit3 = (v2f){t3.y, -t3.x};
    o1 = t1 + nit3;
    o3 = t1 - nit3;
}

static __device__ __forceinline__ void dft8(const v2f* b, v2f* X)
{
    v2f e0, e1, e2, e3, o0, o1, o2, o3;
    dft4(b[0], b[2], b[4], b[6], e0, e1, e2, e3);
    dft4(b[1], b[3], b[5], b[7], o0, o1, o2, o3);
    const float C = 0.70710678118654752f;
    v2f m1 = cmulp(o1, (v2f){ C, -C}, (v2f){C,  C});
    v2f m2 = (v2f){o2.y, -o2.x};
    v2f m3 = cmulp(o3, (v2f){-C, -C}, (v2f){C, -C});
    X[0] = e0 + o0; X[4] = e0 - o0;
    X[1] = e1 + m1; X[5] = e1 - m1;
    X[2] = e2 + m2; X[6] = e2 - m2;
    X[3] = e3 + m3; X[7] = e3 - m3;
}

static __device__ __forceinline__ void dft16(const v2f* a, v2f* X)
{
    v2f y[4][4];
    #pragma unroll
    for (int n2 = 0; n2 < 4; ++n2)
        dft4(a[n2], a[4 + n2], a[8 + n2], a[12 + n2],
             y[n2][0], y[n2][1], y[n2][2], y[n2][3]);
    const float C  = 0.70710678118654752f;
    const float c1 = 0.92387953251128676f, s1 = 0.38268343236508977f;
    y[1][1] = cmulp(y[1][1], (v2f){ c1, -s1}, (v2f){ s1,  c1});
    y[1][2] = cmulp(y[1][2], (v2f){  C,  -C}, (v2f){  C,   C});
    y[1][3] = cmulp(y[1][3], (v2f){ s1, -c1}, (v2f){ c1,  s1});
    y[2][1] = cmulp(y[2][1], (v2f){  C,  -C}, (v2f){  C,   C});
    y[2][2] = (v2f){y[2][2].y, -y[2][2].x};
    y[2][3] = cmulp(y[2][3], (v2f){ -C,  -C}, (v2f){  C,  -C});
    y[3][1] = cmulp(y[3][1], (v2f){ s1, -c1}, (v2f){ c1,  s1});
    y[3][2] = cmulp(y[3][2], (v2f){ -C,  -C}, (v2f){  C,  -C});
    y[3][3] = cmulp(y[3][3], (v2f){-c1,  s1}, (v2f){-s1, -c1});
    #pragma unroll
    for (int k1 = 0; k1 < 4; ++k1)
        dft4(y[0][k1], y[1][k1], y[2][k1], y[3][k1],
             X[k1], X[k1 + 4], X[k1 + 8], X[k1 + 12]);
}

// table lerp weight: w(z) = I0(BETA*sqrt(z)) for z>0 else 0
static __device__ __forceinline__ float kbw(const float* kt, float zz) {
    float t = fmaxf(zz * (float)KBN, 0.0f);
    int i = (int)t;
    float fr = t - (float)i;
    float w = fmaf(fr, kt[i + 1] - kt[i], kt[i]);
    return (zz > 0.f) ? w : 0.f;
}

// ---------------------------------------------------------------------------
// Kernel 0: setup — twiddles + KB weight table + apodization tables
// ---------------------------------------------------------------------------
__global__ __launch_bounds__(256) void setup_kernel(
        float2* __restrict__ tw, float* __restrict__ kbt,
        float* __restrict__ axt, float* __restrict__ ayt)
{
    int idx = blockIdx.x * 256 + threadIdx.x;
    const double TWO_PI = 6.283185307179586476925286766559;
    const float BETA = beta_f();
    const float B2 = (float)(M_PI * M_PI * 19.45);
    const float SCALE = (float)(1.0 / 1099.236098591787);

    if (idx < 1280) {
        double a = -TWO_PI * ((double)idx / 1280.0);
        tw[TW1280_OFF + idx] = make_float2((float)cos(a), (float)sin(a));
    }
    if (idx < 944) {
        double a = -TWO_PI * ((double)idx / 944.0);
        tw[TW944_OFF + idx] = make_float2((float)cos(a), (float)sin(a));
    }
    if (idx < 4097) {
        float z = fminf((float)idx * (1.0f / (float)KBN), 1.0f);
        kbt[idx] = i0f_dev(BETA * sqrtf(z));
    }
    if (idx < IH) {
        float xi = (float)(idx - IH / 2) * (1.0f / (float)GH);
        float px = (float)(M_PI * (double)JW) * xi;
        float sxr = sqrtf(B2 - px * px);
        float ax = (float)JW * sinhf(sxr) / sxr;
        axt[idx] = SCALE / ax;
    }
    if (idx < IW) {
        float yj = (float)(idx - IW / 2) * (1.0f / (float)GW);
        float py = (float)(M_PI * (double)JW) * yj;
        float syr = sqrtf(B2 - py * py);
        float ay = (float)JW * sinhf(syr) / syr;
        ayt[idx] = 1.0f / ay;
    }
}

// ---------------------------------------------------------------------------
// Kernel 1: FUSED apodize+pad+ifftshift+scale + 944-pt row FFT. 4 rows/block.
// Apodization from precomputed tables. Output: packed-bf16 grid.
// ---------------------------------------------------------------------------
__global__ __launch_bounds__(256) void fft_row_kernel(
        const float* __restrict__ ir, const float* __restrict__ ii,
        unsigned int* __restrict__ gridh, const v2f* __restrict__ twg,
        const float* __restrict__ axt, const float* __restrict__ ayt,
        int b0, int nb)
{
    __shared__ v2f buf[4 * 948];          // stride 948 -> r-groups on disjoint banks

    int blk  = blockIdx.x;                // nb*160 blocks
    int lb   = blk / 160;
    int rblk = (blk % 160) * 4;
    int b    = b0 + lb;
    int tid  = threadIdx.x;
    const v2f* tw = twg + TW944_OFF;

    // load + apodize 4 rows (table-based)
    for (int item = tid; item < 4 * 944; item += 256) {
        int v  = item % 944;
        int rr = item / 944;
        int ri = rblk + rr;
        int i  = (ri < 320) ? ri + 320 : ri - 320;          // image row
        v2f val = (v2f){0.f, 0.f};
        int j = -1;
        if (v < (GW - IW) / 2) j = v + IW / 2;              // 236..471
        else if (v >= (GW + IW) / 2) j = v - (GW + IW) / 2; // 0..235
        if (j >= 0) {
            float invA = axt[i] * ayt[j];
            size_t src = ((size_t)(b * IH + i)) * IW + j;
            val.x = ir[src] * invA;
            val.y = ii[src] * invA;
        }
        buf[rr * 948 + v] = val;
    }
    __syncthreads();

    if (tid < 236) {
        int r  = tid / 59;
        int k1 = tid % 59;
        int ri = rblk + r;
        int u  = (ri < 320) ? ri : ri + 640;
        unsigned int* rowp = gridh + ((size_t)(lb * GH + u)) * GWP;
        const v2f* bufr = buf + r * 948;

        v2f acc[16];
        #pragma unroll
        for (int n2 = 0; n2 < 16; ++n2) acc[n2] = (v2f){0.f, 0.f};

        v2f r59 = tw[16 * k1];                        // W59^{k1}
        v2f r59p = perp(r59);
        v2f w = (v2f){1.f, 0.f};
        v2f wp = (v2f){0.f, 1.f};
        for (int n1 = 0; n1 < 15; ++n1) {
            const v4f* pb = (const v4f*)(bufr + (n1 << 4));
            #pragma unroll
            for (int t4 = 0; t4 < 8; ++t4) {
                v4f q = pb[t4];
                v2f c0 = __builtin_shufflevector(q, q, 0, 1);
                v2f c1 = __builtin_shufflevector(q, q, 2, 3);
                cmacp(acc[2 * t4],     c0, w, wp);
                cmacp(acc[2 * t4 + 1], c1, w, wp);
            }
            w = cmulp(w, r59, r59p);
            wp = perp(w);
        }
        w = tw[16 * ((44 * k1) % 59)];                // W59^{44 k1}
        wp = perp(w);
        for (int n1 = 44; n1 < 59; ++n1) {
            const v4f* pb = (const v4f*)(bufr + (n1 << 4));
            #pragma unroll
            for (int t4 = 0; t4 < 8; ++t4) {
                v4f q = pb[t4];
                v2f c0 = __builtin_shufflevector(q, q, 0, 1);
                v2f c1 = __builtin_shufflevector(q, q, 2, 3);
                cmacp(acc[2 * t4],     c0, w, wp);
                cmacp(acc[2 * t4 + 1], c1, w, wp);
            }
            w = cmulp(w, r59, r59p);
            wp = perp(w);
        }

        // inter-stage twiddle W944^{n2 k1} by recurrence
        v2f tstep = tw[k1];
        v2f tstepp = perp(tstep);
        v2f t = (v2f){1.f, 0.f};
        v2f tp = (v2f){0.f, 1.f};
        #pragma unroll
        for (int n2 = 0; n2 < 16; ++n2) {
            acc[n2] = cmulp(acc[n2], t, tp);
            t = cmulp(t, tstep, tstepp);
            tp = perp(t);
        }

        v2f X[16];
        dft16(acc, X);
        #pragma unroll
        for (int q = 0; q < 16; ++q)
            rowp[k1 + 59 * q] = packbf(X[q]);         // coalesced across k1 lanes
    }
}

// ---------------------------------------------------------------------------
// Kernel 2: 1280-pt column FFT (20*8*8), 4 cols/block, fused A+B per thread.
// IN-PLACE on the packed-bf16 grid. Packed (v2f) complex math throughout.
// ---------------------------------------------------------------------------
__global__ __launch_bounds__(256) void fft_col_kernel(
        unsigned int* __restrict__ gridh, const v2f* __restrict__ twg)
{
    __shared__ v2f buf[1280 * NC];        // 40960 B

    int blk = blockIdx.x;                 // nb * 236
    int lb = blk / (GW / NC);
    int vb = blk % (GW / NC);
    unsigned int* baseh = gridh + (size_t)lb * GH * GWP + vb * NC;
    int tid = threadIdx.x;
    const v2f* tw = twg + TW1280_OFF;

    #pragma unroll
    for (int it = 0; it < 10; ++it) {
        int item = it * 256 + tid;
        int c  = item & (NC - 1);
        int up = item >> 2;               // 0..639
        int u  = (up < 320) ? up : up + 640;
        buf[up * NC + c] = unpackbf(baseh[(size_t)u * GWP + c]);
    }
    __syncthreads();

    v2f T[3][8];
    #pragma unroll
    for (int ch = 0; ch < 3; ++ch) {
        int item = ch * 256 + tid;
        if (item < 640) {
            int c  = item & 3;
            int tt = item >> 2;
            int k1 = tt % 20;
            int m2 = tt / 20;

            v2f acc[8];
            #pragma unroll
            for (int j = 0; j < 8; ++j) acc[j] = (v2f){0.f, 0.f};

            v2f r20 = tw[64 * k1];
            v2f r20p = perp(r20);
            v2f w = (v2f){1.f, 0.f};
            v2f wp = (v2f){0.f, 1.f};
            for (int n1 = 0; n1 < 5; ++n1) {
                int ub = (n1 << 6) + m2;
                #pragma unroll
                for (int j = 0; j < 8; ++j)
                    cmacp(acc[j], buf[(ub + (j << 3)) * NC + c], w, wp);
                w = cmulp(w, r20, r20p);
                wp = perp(w);
            }
            w = tw[64 * ((15 * k1) % 20)];
            wp = perp(w);
            for (int n1 = 5; n1 < 10; ++n1) {
                int ub = (n1 << 6) + m2;
                #pragma unroll
                for (int j = 0; j < 8; ++j)
                    cmacp(acc[j], buf[(ub + (j << 3)) * NC + c], w, wp);
                w = cmulp(w, r20, r20p);
                wp = perp(w);
            }

            v2f tpj = tw[m2 * k1];
            v2f tstep = tw[8 * k1];
            v2f tstepp = perp(tstep);
            #pragma unroll
            for (int j = 0; j < 8; ++j) {
                acc[j] = cmulp(acc[j], tpj, perp(tpj));
                tpj = cmulp(tpj, tstep, tstepp);
            }

            dft8(acc, T[ch]);

            v2f wb = tw[20 * m2];
            v2f wbp = perp(wb);
            v2f v = (v2f){1.f, 0.f};
            #pragma unroll
            for (int k21 = 0; k21 < 8; ++k21) {
                T[ch][k21] = cmulp(T[ch][k21], v, perp(v));
                v = cmulp(v, wb, wbp);
            }
        }
    }
    __syncthreads();

    #pragma unroll
    for (int ch = 0; ch < 3; ++ch) {
        int item = ch * 256 + tid;
        if (item < 640) {
            int c  = item & 3;
            int tt = item >> 2;
            int k1 = tt % 20;
            int m2 = tt / 20;
            #pragma unroll
            for (int k21 = 0; k21 < 8; ++k21)
                buf[(((k21 << 3) + m2) * 20 + k1) * NC + c] = T[ch][k21];
        }
    }
    __syncthreads();

    #pragma unroll
    for (int ch = 0; ch < 3; ++ch) {
        int item = ch * 256 + tid;
        if (item < 640) {
            int c   = item & 3;
            int tt  = item >> 2;
            int k1  = tt % 20;
            int k21 = tt / 20;
            v2f bb[8];
            #pragma unroll
            for (int m2 = 0; m2 < 8; ++m2)
                bb[m2] = buf[(((k21 << 3) + m2) * 20 + k1) * NC + c];
            v2f X[8];
            dft8(bb, X);
            #pragma unroll
            for (int k22 = 0; k22 < 8; ++k22) {
                int rrow = k1 + 20 * k21 + 160 * k22;
                unsigned int pk = packbf(X[k22]);
                baseh[(size_t)rrow * GWP + c] = pk;
                if (vb < 2) baseh[(size_t)rrow * GWP + GW + c] = pk;  // echo
            }
        }
    }
}

// ---------------------------------------------------------------------------
// Kernel 3: KB interpolation, 2 POINTS per thread, LDS weight table.
// ---------------------------------------------------------------------------
__global__ __launch_bounds__(256) void interp_kernel(
        const float* __restrict__ ktraj, const unsigned int* __restrict__ gridh,
        const float* __restrict__ kbt,
        float* __restrict__ out, int b0, int nb, int write_complex, int swizzle)
{
    __shared__ float kt[4097];
    for (int t = threadIdx.x; t < 4097; t += 256) kt[t] = kbt[t];
    __syncthreads();

    int lb, pidx;                         // pair index within batch
    if (swizzle) {
        int g = blockIdx.x;               // 784 blocks: 8 XCD slots x 98
        int xcd = g & 7;
        lb = xcd >> 1;
        int slot = ((g >> 3) << 1) | (g & 1);   // 0..195
        pidx = slot * 256 + threadIdx.x;
        if (pidx >= NK / 2) return;
    } else {
        int idx = blockIdx.x * 256 + threadIdx.x;
        if (idx >= nb * (NK / 2)) return;
        lb = idx / (NK / 2);
        pidx = idx % (NK / 2);
    }
    int b = b0 + lb;
    int k0 = 2 * pidx;

    const float sx = (float)((double)GH / (2.0 * M_PI));
    const float sy = (float)((double)GW / (2.0 * M_PI));
    const float* ktx = ktraj + (size_t)(b * 2 + 0) * NK + k0;
    const float* kty = ktraj + (size_t)(b * 2 + 1) * NK + k0;

    float t0[2], t1[2];
    t0[0] = ktx[0] * sx; t0[1] = ktx[1] * sx;
    t1[0] = kty[0] * sy; t1[1] = kty[1] * sy;

    int   ix[2][JW];
    float wx[2][JW];
    float wy12[2][12];
    int   aw[2];
    bool  need3[2];

    #pragma unroll
    for (int pp = 0; pp < 2; ++pp) {
        int base0 = (int)floorf(t0[pp]);
        int base1 = (int)floorf(t1[pp]);
        #pragma unroll
        for (int j = 0; j < JW; ++j) {
            int kx = base0 + j - (JW / 2 - 1);
            float u = t0[pp] - (float)kx;
            float q = u * (1.0f / 3.0f);
            wx[pp][j] = kbw(kt, 1.0f - q * q);
            int m = kx % GH; if (m < 0) m += GH;
            ix[pp][j] = m;
        }
        int j0u = base1 - 2;
        int a0u = j0u & ~3;
        int a = a0u; if (a < 0) a += GW;
        aw[pp] = a;
        need3[pp] = ((j0u & 3) == 3);
        #pragma unroll
        for (int t = 0; t < 12; ++t) {
            float u = t1[pp] - (float)(a0u + t);
            float q = u * (1.0f / 3.0f);
            wy12[pp][t] = kbw(kt, 1.0f - q * q);
        }
    }

    v2f acc[2] = {(v2f){0.f, 0.f}, (v2f){0.f, 0.f}};
    #pragma unroll
    for (int a = 0; a < JW; ++a) {
        #pragma unroll
        for (int pp = 0; pp < 2; ++pp) {
            const uint4* p4 = (const uint4*)(gridh +
                ((size_t)(lb * GH + ix[pp][a])) * GWP + aw[pp]);
            uint4 q0 = p4[0];
            uint4 q1 = p4[1];
            uint4 q2 = need3[pp] ? p4[2] : make_uint4(0u, 0u, 0u, 0u);
            unsigned int qs[12] = {q0.x, q0.y, q0.z, q0.w, q1.x, q1.y, q1.z, q1.w,
                                   q2.x, q2.y, q2.z, q2.w};
            v2f rr = (v2f){0.f, 0.f};
            #pragma unroll
            for (int t = 0; t < 12; ++t)
                rr += wy12[pp][t] * unpackbf(qs[t]);
            acc[pp] += wx[pp][a] * rr;
        }
    }

    size_t p = (size_t)b * NK + k0;
    if (write_complex) {
        float2* oc = (float2*)out;
        oc[p]     = make_float2(acc[0].x, acc[0].y);
        oc[p + 1] = make_float2(acc[1].x, acc[1].y);
    } else {
        out[p]     = acc[0].x;
        out[p + 1] = acc[1].x;
    }
}

// ---------------------------------------------------------------------------
extern "C" void kernel_launch(void* const* d_in, const int* in_sizes, int n_in,
                              void* d_out, int out_size, void* d_ws, size_t ws_size,
                              hipStream_t stream)
{
    const float* ir = (const float*)d_in[0];   // [B,640,472,1] float32
    const float* ii = (const float*)d_in[1];   // [B,640,472,1] float32
    const float* kt = (const float*)d_in[2];   // [B,2,K] float32
    float2* tw   = (float2*)d_ws;
    float*  kbt  = (float*)((char*)d_ws + KB_OFF_B);
    float*  axt  = (float*)((char*)d_ws + AX_OFF_B);
    float*  ayt  = (float*)((char*)d_ws + AY_OFF_B);
    float*  out  = (float*)d_out;

    int write_complex = (out_size >= 2 * BATCH * NK) ? 1 : 0;

    const size_t pb16 = (size_t)GH * GWP * sizeof(unsigned int); // 4.87 MB
    size_t avail = (ws_size > TW_RESERVE_BYTES) ? ws_size - TW_RESERVE_BYTES : 0;
    int nb = 1;
    if (avail >= 4 * pb16)      nb = 4;
    else if (avail >= 2 * pb16) nb = 2;

    unsigned int* gridh = (unsigned int*)((char*)d_ws + TW_RESERVE_BYTES);

    setup_kernel<<<17, 256, 0, stream>>>(tw, kbt, axt, ayt);

    for (int b0 = 0; b0 < BATCH; b0 += nb) {
        fft_row_kernel<<<nb * (IH / 4), 256, 0, stream>>>(ir, ii, gridh, (const v2f*)tw, axt, ayt, b0, nb);
        fft_col_kernel<<<nb * (GW / NC), 256, 0, stream>>>(gridh, (const v2f*)tw);
        if (nb == 4) {
            interp_kernel<<<784, 256, 0, stream>>>(kt, gridh, kbt, out, b0, nb, write_complex, 1);
        } else {
            interp_kernel<<<(nb * (NK / 2) + 255) / 256, 256, 0, stream>>>(kt, gridh, kbt, out, b0, nb, write_complex, 0);
        }
    }
}

// Round 15
// 157.814 us; speedup vs baseline: 1.3283x; 1.0232x over previous
//
#include <hip/hip_runtime.h>
#include <math.h>

// Problem constants (match reference)
#define BATCH 4
#define NK    100000
#define IH    640
#define IW    472
#define GH    1280          // oversampled grid rows = 2*IH   (1280 = 20*8*8)
#define GW    944           // oversampled grid cols = 2*IW   (944  = 59*16)
#define GWP   952           // padded row stride: 8 echo cols (window reach <= 951)
#define JW    6             // KB kernel width

// ws layout (bytes): [tw: 2224 v2f][kb table: 4097 f][apodx: 640 f][apody: 472 f]
#define TW1280_OFF 0
#define TW944_OFF  1280
#define KB_OFF_B   18432
#define AX_OFF_B   34944
#define AY_OFF_B   37504
#define TW_RESERVE_BYTES 65536

#define KBN 4095             // table scale: idx = z*KBN, entries 0..4096

#define NC 4                 // columns per fft_col block

typedef float v2f __attribute__((ext_vector_type(2)));
typedef float v4f __attribute__((ext_vector_type(4)));

static __device__ __forceinline__ float beta_f() {
    return (float)(M_PI * 4.410215414239989);   // pi*sqrt(19.45)
}

// Abramowitz & Stegun I0 approximation (rel err < 2e-7), x >= 0
static __device__ __forceinline__ float i0f_dev(float x) {
    if (x < 3.75f) {
        float t = x * (1.0f / 3.75f);
        t *= t;
        return 1.0f + t*(3.5156229f + t*(3.0899424f + t*(1.2067492f +
               t*(0.2659732f + t*(0.0360768f + t*0.0045813f)))));
    } else {
        float t = 3.75f / x;
        float p = 0.39894228f + t*(0.01328592f + t*(0.00225319f + t*(-0.00157565f +
                  t*(0.00916281f + t*(-0.02057706f + t*(0.02635537f +
                  t*(-0.01647633f + t*0.00392377f)))))));
        return p * expf(x) / sqrtf(x);
    }
}

// ---- packed complex helpers (complex = v2f (re,im); ops lower to v_pk_*_f32)
static __device__ __forceinline__ v2f perp(v2f w) { return (v2f){-w.y, w.x}; }
static __device__ __forceinline__ v2f cmulp(v2f x, v2f w, v2f wp) {
    v2f xr = __builtin_shufflevector(x, x, 0, 0);
    v2f xi = __builtin_shufflevector(x, x, 1, 1);
    return xr * w + xi * wp;
}
static __device__ __forceinline__ v2f cmul(v2f a, v2f b) { return cmulp(a, b, perp(b)); }
static __device__ __forceinline__ void cmacp(v2f& acc, v2f x, v2f w, v2f wp) {
    v2f xr = __builtin_shufflevector(x, x, 0, 0);
    v2f xi = __builtin_shufflevector(x, x, 1, 1);
    acc += xr * w;
    acc += xi * wp;
}

// float -> bf16 bits (round-nearest-even); pack/unpack complex
static __device__ __forceinline__ unsigned int f2bf(float f) {
    unsigned int u = __float_as_uint(f);
    return (u + 0x7FFFu + ((u >> 16) & 1u)) >> 16;
}
static __device__ __forceinline__ unsigned int packbf(v2f v) {
    return f2bf(v.x) | (f2bf(v.y) << 16);
}
static __device__ __forceinline__ v2f unpackbf(unsigned int p) {
    return (v2f){__uint_as_float(p << 16), __uint_as_float(p & 0xFFFF0000u)};
}

// DFT4 (W4 = -i)
static __device__ __forceinline__ void dft4(v2f a0, v2f a1, v2f a2, v2f a3,
                                            v2f& o0, v2f& o1, v2f& o2, v2f& o3)
{
    v2f t0 = a0 + a2, t1 = a0 - a2;
    v2f t2 = a1 + a3, t3 = a1 - a3;
    o0 = t0 + t2;
    o2 = t0 - t2;
    v2f nit3 = (v2f){t3.y, -t3.x};
    o1 = t1 + nit3;
    o3 = t1 - nit3;
}

static __device__ __forceinline__ void dft8(const v2f* b, v2f* X)
{
    v2f e0, e1, e2, e3, o0, o1, o2, o3;
    dft4(b[0], b[2], b[4], b[6], e0, e1, e2, e3);
    dft4(b[1], b[3], b[5], b[7], o0, o1, o2, o3);
    const float C = 0.70710678118654752f;
    v2f m1 = cmulp(o1, (v2f){ C, -C}, (v2f){C,  C});
    v2f m2 = (v2f){o2.y, -o2.x};
    v2f m3 = cmulp(o3, (v2f){-C, -C}, (v2f){C, -C});
    X[0] = e0 + o0; X[4] = e0 - o0;
    X[1] = e1 + m1; X[5] = e1 - m1;
    X[2] = e2 + m2; X[6] = e2 - m2;
    X[3] = e3 + m3; X[7] = e3 - m3;
}

// DFT5 (Winograd-style even/odd split)
static __device__ __forceinline__ void dft5(v2f a0, v2f a1, v2f a2, v2f a3, v2f a4,
                                            v2f* X)
{
    const float c1 = 0.30901699437494742f, s1 = 0.95105651629515353f;   // cos72,sin72
    const float c2 = -0.80901699437494742f, s2 = 0.58778525229247312f;  // cos144,sin144
    v2f t1 = a1 + a4, d1 = a1 - a4;
    v2f t2 = a2 + a3, d2 = a2 - a3;
    X[0] = a0 + t1 + t2;
    v2f e1 = a0 + c1 * t1 + c2 * t2;
    v2f o1 = s1 * d1 + s2 * d2;
    v2f e2 = a0 + c2 * t1 + c1 * t2;
    v2f o2 = s2 * d1 - s1 * d2;
    X[1] = (v2f){e1.x + o1.y, e1.y - o1.x};   // e1 - i*o1
    X[4] = (v2f){e1.x - o1.y, e1.y + o1.x};   // e1 + i*o1
    X[2] = (v2f){e2.x + o2.y, e2.y - o2.x};
    X[3] = (v2f){e2.x - o2.y, e2.y + o2.x};
}

static __device__ __forceinline__ void dft16(const v2f* a, v2f* X)
{
    v2f y[4][4];
    #pragma unroll
    for (int n2 = 0; n2 < 4; ++n2)
        dft4(a[n2], a[4 + n2], a[8 + n2], a[12 + n2],
             y[n2][0], y[n2][1], y[n2][2], y[n2][3]);
    const float C  = 0.70710678118654752f;
    const float c1 = 0.92387953251128676f, s1 = 0.38268343236508977f;
    y[1][1] = cmulp(y[1][1], (v2f){ c1, -s1}, (v2f){ s1,  c1});
    y[1][2] = cmulp(y[1][2], (v2f){  C,  -C}, (v2f){  C,   C});
    y[1][3] = cmulp(y[1][3], (v2f){ s1, -c1}, (v2f){ c1,  s1});
    y[2][1] = cmulp(y[2][1], (v2f){  C,  -C}, (v2f){  C,   C});
    y[2][2] = (v2f){y[2][2].y, -y[2][2].x};
    y[2][3] = cmulp(y[2][3], (v2f){ -C,  -C}, (v2f){  C,  -C});
    y[3][1] = cmulp(y[3][1], (v2f){ s1, -c1}, (v2f){ c1,  s1});
    y[3][2] = cmulp(y[3][2], (v2f){ -C,  -C}, (v2f){  C,  -C});
    y[3][3] = cmulp(y[3][3], (v2f){-c1,  s1}, (v2f){-s1, -c1});
    #pragma unroll
    for (int k1 = 0; k1 < 4; ++k1)
        dft4(y[0][k1], y[1][k1], y[2][k1], y[3][k1],
             X[k1], X[k1 + 4], X[k1 + 8], X[k1 + 12]);
}

// table lerp weight: w(z) = I0(BETA*sqrt(z)) for z>0 else 0
static __device__ __forceinline__ float kbw(const float* kt, float zz) {
    float t = fmaxf(zz * (float)KBN, 0.0f);
    int i = (int)t;
    float fr = t - (float)i;
    float w = fmaf(fr, kt[i + 1] - kt[i], kt[i]);
    return (zz > 0.f) ? w : 0.f;
}

// ---------------------------------------------------------------------------
// Kernel 0: setup — twiddles + KB weight table + apodization tables
// ---------------------------------------------------------------------------
__global__ __launch_bounds__(256) void setup_kernel(
        float2* __restrict__ tw, float* __restrict__ kbt,
        float* __restrict__ axt, float* __restrict__ ayt)
{
    int idx = blockIdx.x * 256 + threadIdx.x;
    const double TWO_PI = 6.283185307179586476925286766559;
    const float BETA = beta_f();
    const float B2 = (float)(M_PI * M_PI * 19.45);
    const float SCALE = (float)(1.0 / 1099.236098591787);

    if (idx < 1280) {
        double a = -TWO_PI * ((double)idx / 1280.0);
        tw[TW1280_OFF + idx] = make_float2((float)cos(a), (float)sin(a));
    }
    if (idx < 944) {
        double a = -TWO_PI * ((double)idx / 944.0);
        tw[TW944_OFF + idx] = make_float2((float)cos(a), (float)sin(a));
    }
    if (idx < 4097) {
        float z = fminf((float)idx * (1.0f / (float)KBN), 1.0f);
        kbt[idx] = i0f_dev(BETA * sqrtf(z));
    }
    if (idx < IH) {
        float xi = (float)(idx - IH / 2) * (1.0f / (float)GH);
        float px = (float)(M_PI * (double)JW) * xi;
        float sxr = sqrtf(B2 - px * px);
        float ax = (float)JW * sinhf(sxr) / sxr;
        axt[idx] = SCALE / ax;
    }
    if (idx < IW) {
        float yj = (float)(idx - IW / 2) * (1.0f / (float)GW);
        float py = (float)(M_PI * (double)JW) * yj;
        float syr = sqrtf(B2 - py * py);
        float ay = (float)JW * sinhf(syr) / syr;
        ayt[idx] = 1.0f / ay;
    }
}

// ---------------------------------------------------------------------------
// Kernel 1: FUSED apodize+pad+ifftshift+scale + 944-pt row FFT. 4 rows/block.
// ---------------------------------------------------------------------------
__global__ __launch_bounds__(256) void fft_row_kernel(
        const float* __restrict__ ir, const float* __restrict__ ii,
        unsigned int* __restrict__ gridh, const v2f* __restrict__ twg,
        const float* __restrict__ axt, const float* __restrict__ ayt,
        int b0, int nb)
{
    __shared__ v2f buf[4 * 948];          // stride 948 -> r-groups on disjoint banks

    int blk  = blockIdx.x;                // nb*160 blocks
    int lb   = blk / 160;
    int rblk = (blk % 160) * 4;
    int b    = b0 + lb;
    int tid  = threadIdx.x;
    const v2f* tw = twg + TW944_OFF;

    // load + apodize 4 rows (table-based)
    for (int item = tid; item < 4 * 944; item += 256) {
        int v  = item % 944;
        int rr = item / 944;
        int ri = rblk + rr;
        int i  = (ri < 320) ? ri + 320 : ri - 320;          // image row
        v2f val = (v2f){0.f, 0.f};
        int j = -1;
        if (v < (GW - IW) / 2) j = v + IW / 2;              // 236..471
        else if (v >= (GW + IW) / 2) j = v - (GW + IW) / 2; // 0..235
        if (j >= 0) {
            float invA = axt[i] * ayt[j];
            size_t src = ((size_t)(b * IH + i)) * IW + j;
            val.x = ir[src] * invA;
            val.y = ii[src] * invA;
        }
        buf[rr * 948 + v] = val;
    }
    __syncthreads();

    if (tid < 236) {
        int r  = tid / 59;
        int k1 = tid % 59;
        int ri = rblk + r;
        int u  = (ri < 320) ? ri : ri + 640;
        unsigned int* rowp = gridh + ((size_t)(lb * GH + u)) * GWP;
        const v2f* bufr = buf + r * 948;

        v2f acc[16];
        #pragma unroll
        for (int n2 = 0; n2 < 16; ++n2) acc[n2] = (v2f){0.f, 0.f};

        v2f r59 = tw[16 * k1];                        // W59^{k1}
        v2f r59p = perp(r59);
        v2f w = (v2f){1.f, 0.f};
        v2f wp = (v2f){0.f, 1.f};
        for (int n1 = 0; n1 < 15; ++n1) {
            const v4f* pb = (const v4f*)(bufr + (n1 << 4));
            #pragma unroll
            for (int t4 = 0; t4 < 8; ++t4) {
                v4f q = pb[t4];
                v2f c0 = __builtin_shufflevector(q, q, 0, 1);
                v2f c1 = __builtin_shufflevector(q, q, 2, 3);
                cmacp(acc[2 * t4],     c0, w, wp);
                cmacp(acc[2 * t4 + 1], c1, w, wp);
            }
            w = cmulp(w, r59, r59p);
            wp = perp(w);
        }
        w = tw[16 * ((44 * k1) % 59)];                // W59^{44 k1}
        wp = perp(w);
        for (int n1 = 44; n1 < 59; ++n1) {
            const v4f* pb = (const v4f*)(bufr + (n1 << 4));
            #pragma unroll
            for (int t4 = 0; t4 < 8; ++t4) {
                v4f q = pb[t4];
                v2f c0 = __builtin_shufflevector(q, q, 0, 1);
                v2f c1 = __builtin_shufflevector(q, q, 2, 3);
                cmacp(acc[2 * t4],     c0, w, wp);
                cmacp(acc[2 * t4 + 1], c1, w, wp);
            }
            w = cmulp(w, r59, r59p);
            wp = perp(w);
        }

        v2f tstep = tw[k1];
        v2f tstepp = perp(tstep);
        v2f t = (v2f){1.f, 0.f};
        v2f tp = (v2f){0.f, 1.f};
        #pragma unroll
        for (int n2 = 0; n2 < 16; ++n2) {
            acc[n2] = cmulp(acc[n2], t, tp);
            t = cmulp(t, tstep, tstepp);
            tp = perp(t);
        }

        v2f X[16];
        dft16(acc, X);
        #pragma unroll
        for (int q = 0; q < 16; ++q)
            rowp[k1 + 59 * q] = packbf(X[q]);         // coalesced across k1 lanes
    }
}

// ---------------------------------------------------------------------------
// Kernel 2: 1280-pt column FFT (20*8*8), 4 cols/block, IN-PLACE packed bf16.
// Stage A restructured: one thread per (m,c) (m<64), x-taps in registers,
// twiddle-free CT 20 = 4x5 (radix-4 over a with only a in {0,3} nonzero ->
// +-1,+-i coefficients; 12 hardcoded W20 twiddles; Winograd DFT-5),
// W1280^{m k1} fixup by recurrence. A-layout slot k1 XOR (m&3) to break the
// m-stride bank degeneracy (16-way -> 4-way).
// ---------------------------------------------------------------------------
__global__ __launch_bounds__(256) void fft_col_kernel(
        unsigned int* __restrict__ gridh, const v2f* __restrict__ twg)
{
    __shared__ v2f buf[1280 * NC];        // 40960 B

    int blk = blockIdx.x;                 // nb * 236
    int lb = blk / (GW / NC);
    int vb = blk % (GW / NC);
    unsigned int* baseh = gridh + (size_t)lb * GH * GWP + vb * NC;
    int tid = threadIdx.x;
    const v2f* tw = twg + TW1280_OFF;

    // load nonzero rows compacted: u' = u<320 ? u : u-640
    #pragma unroll
    for (int it = 0; it < 10; ++it) {
        int item = it * 256 + tid;
        int c  = item & (NC - 1);
        int up = item >> 2;               // 0..639
        int u  = (up < 320) ? up : up + 640;
        buf[up * NC + c] = unpackbf(baseh[(size_t)u * GWP + c]);
    }
    __syncthreads();

    // ---- stage A: thread (m,c) computes A'[k1][m] for all 20 k1
    {
        int c = tid & 3;
        int m = tid >> 2;                 // 0..63
        v2f x[10];
        #pragma unroll
        for (int n = 0; n < 10; ++n)
            x[n] = buf[(n * 64 + m) * NC + c];
        __syncthreads();                  // all x reads done before A' writes

        // radix-4 over a (nonzero a in {0,3}): A[b][ka] = x[b] + (i^ka)*x[5+b]
        v2f A[5][4];
        #pragma unroll
        for (int bq = 0; bq < 5; ++bq) {
            v2f x0 = x[bq], x3 = x[5 + bq];
            v2f ix3 = (v2f){-x3.y, x3.x};           // i*x3
            A[bq][0] = x0 + x3;
            A[bq][1] = x0 + ix3;
            A[bq][2] = x0 - x3;
            A[bq][3] = x0 - ix3;
        }
        // W20^{b*ka} twiddles (hardcoded; W20^e = (cos(pi e/10), -sin(pi e/10)))
        const v2f T1  = (v2f){ 0.95105651629515353f, -0.30901699437494742f};
        const v2f T2  = (v2f){ 0.80901699437494742f, -0.58778525229247312f};
        const v2f T3  = (v2f){ 0.58778525229247312f, -0.80901699437494742f};
        const v2f T4  = (v2f){ 0.30901699437494742f, -0.95105651629515353f};
        const v2f T6  = (v2f){-0.30901699437494742f, -0.95105651629515353f};
        const v2f T8  = (v2f){-0.80901699437494742f, -0.58778525229247312f};
        const v2f T9  = (v2f){-0.95105651629515353f, -0.30901699437494742f};
        const v2f T12 = (v2f){-0.80901699437494742f,  0.58778525229247312f};
        A[1][1] = cmul(A[1][1], T1);  A[2][1] = cmul(A[2][1], T2);
        A[3][1] = cmul(A[3][1], T3);  A[4][1] = cmul(A[4][1], T4);
        A[1][2] = cmul(A[1][2], T2);  A[2][2] = cmul(A[2][2], T4);
        A[3][2] = cmul(A[3][2], T6);  A[4][2] = cmul(A[4][2], T8);
        A[1][3] = cmul(A[1][3], T3);  A[2][3] = cmul(A[2][3], T6);
        A[3][3] = cmul(A[3][3], T9);  A[4][3] = cmul(A[4][3], T12);

        v2f wstep = tw[4 * m];
        v2f wstepp = perp(wstep);
        #pragma unroll
        for (int ka = 0; ka < 4; ++ka) {
            v2f Y[5];
            dft5(A[0][ka], A[1][ka], A[2][ka], A[3][ka], A[4][ka], Y);
            v2f w = (ka == 0) ? (v2f){1.f, 0.f} : tw[m * ka];  // W1280^{m ka}
            #pragma unroll
            for (int kb = 0; kb < 5; ++kb) {
                int k1 = ka + 4 * kb;
                v2f outv = cmulp(Y[kb], w, perp(w));
                buf[(m * 20 + (k1 ^ (m & 3))) * NC + c] = outv;
                w = cmulp(w, wstep, wstepp);       // *= W1280^{4m}
            }
        }
    }
    __syncthreads();

    // ---- stage B: DFT8 over m1 + W64 fixup (reads A-layout with XOR swizzle)
    v2f T[3][8];
    #pragma unroll
    for (int ch = 0; ch < 3; ++ch) {
        int item = ch * 256 + tid;
        if (item < 640) {
            int c  = item & 3;
            int tt = item >> 2;
            int k1 = tt % 20;
            int m2 = tt / 20;

            v2f bb[8];
            #pragma unroll
            for (int m1 = 0; m1 < 8; ++m1) {
                int m = (m1 << 3) + m2;
                bb[m1] = buf[(m * 20 + (k1 ^ (m2 & 3))) * NC + c];
            }
            dft8(bb, T[ch]);

            v2f wb = tw[20 * m2];                  // W64^{m2}
            v2f wbp = perp(wb);
            v2f v = (v2f){1.f, 0.f};
            #pragma unroll
            for (int k21 = 0; k21 < 8; ++k21) {
                T[ch][k21] = cmulp(T[ch][k21], v, perp(v));
                v = cmulp(v, wb, wbp);
            }
        }
    }
    __syncthreads();

    #pragma unroll
    for (int ch = 0; ch < 3; ++ch) {
        int item = ch * 256 + tid;
        if (item < 640) {
            int c  = item & 3;
            int tt = item >> 2;
            int k1 = tt % 20;
            int m2 = tt / 20;
            #pragma unroll
            for (int k21 = 0; k21 < 8; ++k21)
                buf[(((k21 << 3) + m2) * 20 + k1) * NC + c] = T[ch][k21];
        }
    }
    __syncthreads();

    // ---- stage C: DFT8 over m2 -> packed bf16 global (in place)
    #pragma unroll
    for (int ch = 0; ch < 3; ++ch) {
        int item = ch * 256 + tid;
        if (item < 640) {
            int c   = item & 3;
            int tt  = item >> 2;
            int k1  = tt % 20;
            int k21 = tt / 20;
            v2f bb[8];
            #pragma unroll
            for (int m2 = 0; m2 < 8; ++m2)
                bb[m2] = buf[(((k21 << 3) + m2) * 20 + k1) * NC + c];
            v2f X[8];
            dft8(bb, X);
            #pragma unroll
            for (int k22 = 0; k22 < 8; ++k22) {
                int rrow = k1 + 20 * k21 + 160 * k22;
                unsigned int pk = packbf(X[k22]);
                baseh[(size_t)rrow * GWP + c] = pk;
                if (vb < 2) baseh[(size_t)rrow * GWP + GW + c] = pk;  // echo
            }
        }
    }
}

// ---------------------------------------------------------------------------
// Kernel 3: KB interpolation, 2 POINTS per thread, LDS weight table.
// ---------------------------------------------------------------------------
__global__ __launch_bounds__(256) void interp_kernel(
        const float* __restrict__ ktraj, const unsigned int* __restrict__ gridh,
        const float* __restrict__ kbt,
        float* __restrict__ out, int b0, int nb, int write_complex, int swizzle)
{
    __shared__ float kt[4097];
    for (int t = threadIdx.x; t < 4097; t += 256) kt[t] = kbt[t];
    __syncthreads();

    int lb, pidx;
    if (swizzle) {
        int g = blockIdx.x;               // 784 blocks: 8 XCD slots x 98
        int xcd = g & 7;
        lb = xcd >> 1;
        int slot = ((g >> 3) << 1) | (g & 1);
        pidx = slot * 256 + threadIdx.x;
        if (pidx >= NK / 2) return;
    } else {
        int idx = blockIdx.x * 256 + threadIdx.x;
        if (idx >= nb * (NK / 2)) return;
        lb = idx / (NK / 2);
        pidx = idx % (NK / 2);
    }
    int b = b0 + lb;
    int k0 = 2 * pidx;

    const float sx = (float)((double)GH / (2.0 * M_PI));
    const float sy = (float)((double)GW / (2.0 * M_PI));
    const float* ktx = ktraj + (size_t)(b * 2 + 0) * NK + k0;
    const float* kty = ktraj + (size_t)(b * 2 + 1) * NK + k0;

    float t0[2], t1[2];
    t0[0] = ktx[0] * sx; t0[1] = ktx[1] * sx;
    t1[0] = kty[0] * sy; t1[1] = kty[1] * sy;

    int   ix[2][JW];
    float wx[2][JW];
    float wy12[2][12];
    int   aw[2];
    bool  need3[2];

    #pragma unroll
    for (int pp = 0; pp < 2; ++pp) {
        int base0 = (int)floorf(t0[pp]);
        int base1 = (int)floorf(t1[pp]);
        #pragma unroll
        for (int j = 0; j < JW; ++j) {
            int kx = base0 + j - (JW / 2 - 1);
            float u = t0[pp] - (float)kx;
            float q = u * (1.0f / 3.0f);
            wx[pp][j] = kbw(kt, 1.0f - q * q);
            int m = kx % GH; if (m < 0) m += GH;
            ix[pp][j] = m;
        }
        int j0u = base1 - 2;
        int a0u = j0u & ~3;
        int a = a0u; if (a < 0) a += GW;
        aw[pp] = a;
        need3[pp] = ((j0u & 3) == 3);
        #pragma unroll
        for (int t = 0; t < 12; ++t) {
            float u = t1[pp] - (float)(a0u + t);
            float q = u * (1.0f / 3.0f);
            wy12[pp][t] = kbw(kt, 1.0f - q * q);
        }
    }

    v2f acc[2] = {(v2f){0.f, 0.f}, (v2f){0.f, 0.f}};
    #pragma unroll
    for (int a = 0; a < JW; ++a) {
        #pragma unroll
        for (int pp = 0; pp < 2; ++pp) {
            const uint4* p4 = (const uint4*)(gridh +
                ((size_t)(lb * GH + ix[pp][a])) * GWP + aw[pp]);
            uint4 q0 = p4[0];
            uint4 q1 = p4[1];
            uint4 q2 = need3[pp] ? p4[2] : make_uint4(0u, 0u, 0u, 0u);
            unsigned int qs[12] = {q0.x, q0.y, q0.z, q0.w, q1.x, q1.y, q1.z, q1.w,
                                   q2.x, q2.y, q2.z, q2.w};
            v2f rr = (v2f){0.f, 0.f};
            #pragma unroll
            for (int t = 0; t < 12; ++t)
                rr += wy12[pp][t] * unpackbf(qs[t]);
            acc[pp] += wx[pp][a] * rr;
        }
    }

    size_t p = (size_t)b * NK + k0;
    if (write_complex) {
        float2* oc = (float2*)out;
        oc[p]     = make_float2(acc[0].x, acc[0].y);
        oc[p + 1] = make_float2(acc[1].x, acc[1].y);
    } else {
        out[p]     = acc[0].x;
        out[p + 1] = acc[1].x;
    }
}

// ---------------------------------------------------------------------------
extern "C" void kernel_launch(void* const* d_in, const int* in_sizes, int n_in,
                              void* d_out, int out_size, void* d_ws, size_t ws_size,
                              hipStream_t stream)
{
    const float* ir = (const float*)d_in[0];   // [B,640,472,1] float32
    const float* ii = (const float*)d_in[1];   // [B,640,472,1] float32
    const float* kt = (const float*)d_in[2];   // [B,2,K] float32
    float2* tw   = (float2*)d_ws;
    float*  kbt  = (float*)((char*)d_ws + KB_OFF_B);
    float*  axt  = (float*)((char*)d_ws + AX_OFF_B);
    float*  ayt  = (float*)((char*)d_ws + AY_OFF_B);
    float*  out  = (float*)d_out;

    int write_complex = (out_size >= 2 * BATCH * NK) ? 1 : 0;

    const size_t pb16 = (size_t)GH * GWP * sizeof(unsigned int); // 4.87 MB
    size_t avail = (ws_size > TW_RESERVE_BYTES) ? ws_size - TW_RESERVE_BYTES : 0;
    int nb = 1;
    if (avail >= 4 * pb16)      nb = 4;
    else if (avail >= 2 * pb16) nb = 2;

    unsigned int* gridh = (unsigned int*)((char*)d_ws + TW_RESERVE_BYTES);

    setup_kernel<<<17, 256, 0, stream>>>(tw, kbt, axt, ayt);

    for (int b0 = 0; b0 < BATCH; b0 += nb) {
        fft_row_kernel<<<nb * (IH / 4), 256, 0, stream>>>(ir, ii, gridh, (const v2f*)tw, axt, ayt, b0, nb);
        fft_col_kernel<<<nb * (GW / NC), 256, 0, stream>>>(gridh, (const v2f*)tw);
        if (nb == 4) {
            interp_kernel<<<784, 256, 0, stream>>>(kt, gridh, kbt, out, b0, nb, write_complex, 1);
        } else {
            interp_kernel<<<(nb * (NK / 2) + 255) / 256, 256, 0, stream>>>(kt, gridh, kbt, out, b0, nb, write_complex, 0);
        }
    }
}